// Round 1
// baseline (1136.834 us; speedup 1.0000x reference)
//
#include <hip/hip_runtime.h>
#include <math.h>

#define B_ 4
#define T_ 2048
#define C_ 512
#define H_ 8
#define D_ 64
#define CDR_HEADS_ 2
#define NROWS (B_ * T_)          // 8192

// ---------------------------------------------------------------------------
// Kernel 1: per-sample flag — is the CDR mask enabled (any cdrs_score != 0)?
// ---------------------------------------------------------------------------
__global__ void cdr_flag_kernel(const int* __restrict__ cdrs, int* __restrict__ flag) {
    __shared__ int s_any;
    if (threadIdx.x == 0) s_any = 0;
    __syncthreads();
    const int b = blockIdx.x;
    int found = 0;
    for (int t = threadIdx.x; t < T_; t += blockDim.x)
        found |= (cdrs[b * T_ + t] != 0);
    if (found) s_any = 1;          // benign same-value race
    __syncthreads();
    if (threadIdx.x == 0) flag[b] = s_any;   // 1 = CDR masking active for sample b
}

// ---------------------------------------------------------------------------
// Tiled fp32 GEMM body: out = A[M,C_] @ W[C_,C_] + bias, M = NROWS.
// LAYOUT 0: row-major [M, C_].  LAYOUT 1: heads layout [B,H,T,D].
// 64x64 tile, BK=16, 256 threads, 4x4 per thread.
// ---------------------------------------------------------------------------
template <int LAYOUT>
__device__ __forceinline__ void gemm_body(const float* __restrict__ A,
                                          const float* __restrict__ W,
                                          const float* __restrict__ bias,
                                          float* __restrict__ out) {
    __shared__ float As[64][17];   // [m][k], +1 pad
    __shared__ float Bs[16][64];   // [k][n]

    const int tid = threadIdx.x;
    const int tx = tid & 15;       // n quadrant
    const int ty = tid >> 4;       // m quadrant
    const int m0 = blockIdx.x * 64;
    const int n0 = blockIdx.y * 64;

    const int arow = tid >> 2;     // 0..63
    const int akq  = tid & 3;      // 0..3
    const int brow = tid >> 4;     // 0..15
    const int bnq  = tid & 15;     // 0..15

    float acc[4][4] = {};

    for (int k0 = 0; k0 < C_; k0 += 16) {
        float4 av = *(const float4*)(A + (size_t)(m0 + arow) * C_ + k0 + akq * 4);
        float4 bv = *(const float4*)(W + (size_t)(k0 + brow) * C_ + n0 + bnq * 4);
        As[arow][akq * 4 + 0] = av.x;
        As[arow][akq * 4 + 1] = av.y;
        As[arow][akq * 4 + 2] = av.z;
        As[arow][akq * 4 + 3] = av.w;
        *(float4*)&Bs[brow][bnq * 4] = bv;
        __syncthreads();
#pragma unroll
        for (int kk = 0; kk < 16; ++kk) {
            const float a0 = As[ty * 4 + 0][kk];
            const float a1 = As[ty * 4 + 1][kk];
            const float a2 = As[ty * 4 + 2][kk];
            const float a3 = As[ty * 4 + 3][kk];
            const float4 b4 = *(const float4*)&Bs[kk][tx * 4];
            acc[0][0] += a0 * b4.x; acc[0][1] += a0 * b4.y; acc[0][2] += a0 * b4.z; acc[0][3] += a0 * b4.w;
            acc[1][0] += a1 * b4.x; acc[1][1] += a1 * b4.y; acc[1][2] += a1 * b4.z; acc[1][3] += a1 * b4.w;
            acc[2][0] += a2 * b4.x; acc[2][1] += a2 * b4.y; acc[2][2] += a2 * b4.z; acc[2][3] += a2 * b4.w;
            acc[3][0] += a3 * b4.x; acc[3][1] += a3 * b4.y; acc[3][2] += a3 * b4.z; acc[3][3] += a3 * b4.w;
        }
        __syncthreads();
    }

    const float4 bb = *(const float4*)(bias + n0 + tx * 4);
#pragma unroll
    for (int i = 0; i < 4; ++i) {
        const int gm = m0 + ty * 4 + i;
        float4 o;
        o.x = acc[i][0] + bb.x;
        o.y = acc[i][1] + bb.y;
        o.z = acc[i][2] + bb.z;
        o.w = acc[i][3] + bb.w;
        if (LAYOUT == 0) {
            *(float4*)(out + (size_t)gm * C_ + n0 + tx * 4) = o;
        } else {
            const int b = gm >> 11;          // / T_
            const int t = gm & (T_ - 1);
            const int h = n0 >> 6;           // 64-col block == one head
            const int d = tx * 4;
            *(float4*)(out + (((size_t)(b * H_ + h) * T_ + t) * D_) + d) = o;
        }
    }
}

// Q, K, V in one launch (blockIdx.z selects matrix), heads layout output.
__global__ __launch_bounds__(256) void gemm_qkv_kernel(
    const float* __restrict__ x,
    const float* __restrict__ Wq, const float* __restrict__ bq,
    const float* __restrict__ Wk, const float* __restrict__ bk,
    const float* __restrict__ Wv, const float* __restrict__ bv,
    float* __restrict__ q, float* __restrict__ k, float* __restrict__ v) {
    if (blockIdx.z == 0)      gemm_body<1>(x, Wq, bq, q);
    else if (blockIdx.z == 1) gemm_body<1>(x, Wk, bk, k);
    else                      gemm_body<1>(x, Wv, bv, v);
}

__global__ __launch_bounds__(256) void gemm_out_kernel(
    const float* __restrict__ ctx, const float* __restrict__ Wo,
    const float* __restrict__ bo, float* __restrict__ out) {
    gemm_body<0>(ctx, Wo, bo, out);
}

// ---------------------------------------------------------------------------
// Kernel 3: flash attention, fp32. One thread per query row. 256 q/block.
// K/V tiles of 64 rows staged in LDS; online softmax with mask-skip.
// ---------------------------------------------------------------------------
#define BKV 64

__global__ __launch_bounds__(256) void attn_kernel(
    const float* __restrict__ q, const float* __restrict__ k,
    const float* __restrict__ v, const int* __restrict__ mask,
    const int* __restrict__ cdrs, const int* __restrict__ cdrflag,
    float* __restrict__ ctx) {
    __shared__ float Ks[BKV][D_];
    __shared__ float Vs[BKV][D_];
    __shared__ int validS[BKV];

    const int tid = threadIdx.x;
    const int qtiles = T_ / 256;
    const int qt = blockIdx.x % qtiles;
    const int h  = (blockIdx.x / qtiles) % H_;
    const int b  = blockIdx.x / (qtiles * H_);
    const int t  = qt * 256 + tid;

    // load & pre-scale this thread's query row
    const float* qrow = q + ((size_t)(b * H_ + h) * T_ + t) * D_;
    float qr[D_];
#pragma unroll
    for (int d4 = 0; d4 < D_ / 4; ++d4) {
        const float4 tmp = ((const float4*)qrow)[d4];
        qr[d4 * 4 + 0] = tmp.x * 0.125f;   // 1/sqrt(D)
        qr[d4 * 4 + 1] = tmp.y * 0.125f;
        qr[d4 * 4 + 2] = tmp.z * 0.125f;
        qr[d4 * 4 + 3] = tmp.w * 0.125f;
    }

    float acc[D_];
#pragma unroll
    for (int d = 0; d < D_; ++d) acc[d] = 0.f;
    float m = -INFINITY, l = 0.f;

    const bool isCdrHead = (h < CDR_HEADS_) && (cdrflag[b] != 0);
    const float* kbase = k + (size_t)(b * H_ + h) * T_ * D_;
    const float* vbase = v + (size_t)(b * H_ + h) * T_ * D_;

    for (int kt = 0; kt < T_; kt += BKV) {
        __syncthreads();   // protect LDS from previous iteration's readers
        {
            const float4* ksrc = (const float4*)(kbase + (size_t)kt * D_);
            const float4* vsrc = (const float4*)(vbase + (size_t)kt * D_);
            float4* kdst = (float4*)&Ks[0][0];
            float4* vdst = (float4*)&Vs[0][0];
#pragma unroll
            for (int i = 0; i < 4; ++i) {
                kdst[tid + i * 256] = ksrc[tid + i * 256];
                vdst[tid + i * 256] = vsrc[tid + i * 256];
            }
            if (tid < BKV) {
                const int key = kt + tid;
                int valid = (mask[b * T_ + key] != 0);
                if (isCdrHead && cdrs[b * T_ + key] == 0) valid = 0;
                validS[tid] = valid;
            }
        }
        __syncthreads();

        for (int key = 0; key < BKV; ++key) {
            if (!validS[key]) continue;            // block-uniform branch
            const float4* krow4 = (const float4*)&Ks[key][0];
            float s = 0.f;
#pragma unroll
            for (int d4 = 0; d4 < 16; ++d4) {
                const float4 kk = krow4[d4];
                s += qr[d4 * 4 + 0] * kk.x + qr[d4 * 4 + 1] * kk.y +
                     qr[d4 * 4 + 2] * kk.z + qr[d4 * 4 + 3] * kk.w;
            }
            const float4* vrow4 = (const float4*)&Vs[key][0];
            if (s <= m) {
                const float p = __expf(s - m);
                l += p;
#pragma unroll
                for (int d4 = 0; d4 < 16; ++d4) {
                    const float4 vv = vrow4[d4];
                    acc[d4 * 4 + 0] += p * vv.x;
                    acc[d4 * 4 + 1] += p * vv.y;
                    acc[d4 * 4 + 2] += p * vv.z;
                    acc[d4 * 4 + 3] += p * vv.w;
                }
            } else {
                const float r = __expf(m - s);     // exp(-inf)=0 on first hit
                m = s;
                l = l * r + 1.f;
#pragma unroll
                for (int d4 = 0; d4 < 16; ++d4) {
                    const float4 vv = vrow4[d4];
                    acc[d4 * 4 + 0] = acc[d4 * 4 + 0] * r + vv.x;
                    acc[d4 * 4 + 1] = acc[d4 * 4 + 1] * r + vv.y;
                    acc[d4 * 4 + 2] = acc[d4 * 4 + 2] * r + vv.z;
                    acc[d4 * 4 + 3] = acc[d4 * 4 + 3] * r + vv.w;
                }
            }
        }
    }

    const float inv = 1.f / l;
    float* crow = ctx + ((size_t)(b * T_) + t) * C_ + h * D_;
#pragma unroll
    for (int d4 = 0; d4 < 16; ++d4) {
        float4 o;
        o.x = acc[d4 * 4 + 0] * inv;
        o.y = acc[d4 * 4 + 1] * inv;
        o.z = acc[d4 * 4 + 2] * inv;
        o.w = acc[d4 * 4 + 3] * inv;
        ((float4*)crow)[d4] = o;
    }
}

// ---------------------------------------------------------------------------
extern "C" void kernel_launch(void* const* d_in, const int* in_sizes, int n_in,
                              void* d_out, int out_size, void* d_ws, size_t ws_size,
                              hipStream_t stream) {
    const float* x    = (const float*)d_in[0];
    const int*   mask = (const int*)d_in[1];
    const int*   cdrs = (const int*)d_in[2];
    const float* Wq   = (const float*)d_in[3];
    const float* bq   = (const float*)d_in[4];
    const float* Wk   = (const float*)d_in[5];
    const float* bk   = (const float*)d_in[6];
    const float* Wv   = (const float*)d_in[7];
    const float* bv   = (const float*)d_in[8];
    const float* Wo   = (const float*)d_in[9];
    const float* bo   = (const float*)d_in[10];
    float* out = (float*)d_out;

    const size_t per = (size_t)B_ * H_ * T_ * D_;   // 4M floats
    float* qbuf   = (float*)d_ws;
    float* kbuf   = qbuf + per;
    float* vbuf   = kbuf + per;
    float* ctxbuf = vbuf + per;
    int*   cflag  = (int*)(ctxbuf + (size_t)NROWS * C_);

    cdr_flag_kernel<<<B_, 256, 0, stream>>>(cdrs, cflag);

    dim3 gqkv(NROWS / 64, C_ / 64, 3);
    gemm_qkv_kernel<<<gqkv, 256, 0, stream>>>(x, Wq, bq, Wk, bk, Wv, bv,
                                              qbuf, kbuf, vbuf);

    attn_kernel<<<B_ * H_ * (T_ / 256), 256, 0, stream>>>(
        qbuf, kbuf, vbuf, mask, cdrs, cflag, ctxbuf);

    dim3 gout(NROWS / 64, C_ / 64, 1);
    gemm_out_kernel<<<gout, 256, 0, stream>>>(ctxbuf, Wo, bo, out);
}

// Round 2
// 899.338 us; speedup vs baseline: 1.2641x; 1.2641x over previous
//
#include <hip/hip_runtime.h>
#include <math.h>

#define B_ 4
#define T_ 2048
#define C_ 512
#define H_ 8
#define D_ 64
#define CDR_HEADS_ 2
#define NROWS (B_ * T_)          // 8192
#define LP 68                    // padded LDS row stride in words (16B-aligned: 272B)

// ---------------------------------------------------------------------------
// Kernel 1: per-sample key-list compaction.
// listA (sel=0): keys with mask!=0                  -> heads 2..7
// listB (sel=1): mask!=0 && (any(cdrs)? cdrs!=0:1)  -> heads 0..1
// ---------------------------------------------------------------------------
__global__ __launch_bounds__(256) void compact_kernel(
    const int* __restrict__ mask, const int* __restrict__ cdrs,
    int* __restrict__ klist, int* __restrict__ kcnt) {
    __shared__ int s_any;
    __shared__ int sa[256], sb[256];
    const int b = blockIdx.x, tid = threadIdx.x;
    if (tid == 0) s_any = 0;
    __syncthreads();

    // contiguous 8-element segment per thread (keeps list order stable)
    int m8[8], c8[8];
    int any = 0, ca = 0;
    const int base = b * T_ + tid * 8;
#pragma unroll
    for (int i = 0; i < 8; ++i) {
        m8[i] = mask[base + i];
        c8[i] = cdrs[base + i];
        any |= c8[i];
        ca += (m8[i] != 0);
    }
    if (any) s_any = 1;          // benign same-value race
    __syncthreads();
    const int en = s_any;        // CDR masking enabled for this sample?

    int cb = 0;
#pragma unroll
    for (int i = 0; i < 8; ++i)
        cb += (m8[i] != 0 && (!en || c8[i] != 0));

    sa[tid] = ca; sb[tid] = cb;
    __syncthreads();
    // Hillis-Steele inclusive scan over 256 entries (both arrays)
    for (int off = 1; off < 256; off <<= 1) {
        int va = 0, vb = 0;
        if (tid >= off) { va = sa[tid - off]; vb = sb[tid - off]; }
        __syncthreads();
        sa[tid] += va; sb[tid] += vb;
        __syncthreads();
    }

    int offA = sa[tid] - ca;     // exclusive prefix
    int offB = sb[tid] - cb;
    int* la = klist + (size_t)(b * 2 + 0) * T_;
    int* lb = klist + (size_t)(b * 2 + 1) * T_;
#pragma unroll
    for (int i = 0; i < 8; ++i) {
        const int t = tid * 8 + i;
        if (m8[i] != 0) la[offA++] = t;
        if (m8[i] != 0 && (!en || c8[i] != 0)) lb[offB++] = t;
    }
    if (tid == 255) {
        kcnt[b * 2 + 0] = sa[255];
        kcnt[b * 2 + 1] = sb[255];
    }
}

// ---------------------------------------------------------------------------
// Tiled fp32 GEMM body (unchanged from R0): out = A[M,C_] @ W[C_,C_] + bias.
// LAYOUT 0: row-major [M, C_].  LAYOUT 1: heads layout [B,H,T,D].
// ---------------------------------------------------------------------------
template <int LAYOUT>
__device__ __forceinline__ void gemm_body(const float* __restrict__ A,
                                          const float* __restrict__ W,
                                          const float* __restrict__ bias,
                                          float* __restrict__ out) {
    __shared__ float As[64][17];
    __shared__ float Bs[16][64];

    const int tid = threadIdx.x;
    const int tx = tid & 15;
    const int ty = tid >> 4;
    const int m0 = blockIdx.x * 64;
    const int n0 = blockIdx.y * 64;

    const int arow = tid >> 2;
    const int akq  = tid & 3;
    const int brow = tid >> 4;
    const int bnq  = tid & 15;

    float acc[4][4] = {};

    for (int k0 = 0; k0 < C_; k0 += 16) {
        float4 av = *(const float4*)(A + (size_t)(m0 + arow) * C_ + k0 + akq * 4);
        float4 bv = *(const float4*)(W + (size_t)(k0 + brow) * C_ + n0 + bnq * 4);
        As[arow][akq * 4 + 0] = av.x;
        As[arow][akq * 4 + 1] = av.y;
        As[arow][akq * 4 + 2] = av.z;
        As[arow][akq * 4 + 3] = av.w;
        *(float4*)&Bs[brow][bnq * 4] = bv;
        __syncthreads();
#pragma unroll
        for (int kk = 0; kk < 16; ++kk) {
            const float a0 = As[ty * 4 + 0][kk];
            const float a1 = As[ty * 4 + 1][kk];
            const float a2 = As[ty * 4 + 2][kk];
            const float a3 = As[ty * 4 + 3][kk];
            const float4 b4 = *(const float4*)&Bs[kk][tx * 4];
            acc[0][0] += a0 * b4.x; acc[0][1] += a0 * b4.y; acc[0][2] += a0 * b4.z; acc[0][3] += a0 * b4.w;
            acc[1][0] += a1 * b4.x; acc[1][1] += a1 * b4.y; acc[1][2] += a1 * b4.z; acc[1][3] += a1 * b4.w;
            acc[2][0] += a2 * b4.x; acc[2][1] += a2 * b4.y; acc[2][2] += a2 * b4.z; acc[2][3] += a2 * b4.w;
            acc[3][0] += a3 * b4.x; acc[3][1] += a3 * b4.y; acc[3][2] += a3 * b4.z; acc[3][3] += a3 * b4.w;
        }
        __syncthreads();
    }

    const float4 bb = *(const float4*)(bias + n0 + tx * 4);
#pragma unroll
    for (int i = 0; i < 4; ++i) {
        const int gm = m0 + ty * 4 + i;
        float4 o;
        o.x = acc[i][0] + bb.x;
        o.y = acc[i][1] + bb.y;
        o.z = acc[i][2] + bb.z;
        o.w = acc[i][3] + bb.w;
        if (LAYOUT == 0) {
            *(float4*)(out + (size_t)gm * C_ + n0 + tx * 4) = o;
        } else {
            const int b = gm >> 11;
            const int t = gm & (T_ - 1);
            const int h = n0 >> 6;
            const int d = tx * 4;
            *(float4*)(out + (((size_t)(b * H_ + h) * T_ + t) * D_) + d) = o;
        }
    }
}

__global__ __launch_bounds__(256) void gemm_qkv_kernel(
    const float* __restrict__ x,
    const float* __restrict__ Wq, const float* __restrict__ bq,
    const float* __restrict__ Wk, const float* __restrict__ bk,
    const float* __restrict__ Wv, const float* __restrict__ bv,
    float* __restrict__ q, float* __restrict__ k, float* __restrict__ v) {
    if (blockIdx.z == 0)      gemm_body<1>(x, Wq, bq, q);
    else if (blockIdx.z == 1) gemm_body<1>(x, Wk, bk, k);
    else                      gemm_body<1>(x, Wv, bv, v);
}

__global__ __launch_bounds__(256) void gemm_out_kernel(
    const float* __restrict__ ctx, const float* __restrict__ Wo,
    const float* __restrict__ bo, float* __restrict__ out) {
    gemm_body<0>(ctx, Wo, bo, out);
}

// ---------------------------------------------------------------------------
// Kernel 3: tiled flash attention over COMPACTED key lists.
// Block: 64 queries x 64 keys per tile, 16x16 threads.
// Thread (ty,tx): scores for q rows {ty+16i} x keys {tx+16j} (4x4 regs),
// ctx acc for q rows {ty+16i} x d cols {tx*4..+3} (4x4 regs).
// PV: P broadcast via width-16 shuffles; V read 1x b128/key/thread.
// ---------------------------------------------------------------------------
__global__ __launch_bounds__(256) void attn_kernel(
    const float* __restrict__ q, const float* __restrict__ k,
    const float* __restrict__ v, const int* __restrict__ klist,
    const int* __restrict__ kcnt, float* __restrict__ ctx) {
    __shared__ float Qs[64 * LP];
    __shared__ float Ks[64 * LP];
    __shared__ float Vs[64 * LP];

    const int tid = threadIdx.x;
    const int tx = tid & 15;
    const int ty = tid >> 4;
    const int qt = blockIdx.x;
    const int h  = blockIdx.y;
    const int b  = blockIdx.z;

    const int sel = (h < CDR_HEADS_) ? 1 : 0;
    const int NV = kcnt[b * 2 + sel];
    const int* __restrict__ list = klist + (size_t)(b * 2 + sel) * T_;

    const float* qbase = q + ((size_t)(b * H_ + h) * T_ + qt * 64) * D_;
    const float* kbase = k + (size_t)(b * H_ + h) * T_ * D_;
    const float* vbase = v + (size_t)(b * H_ + h) * T_ * D_;

    // stage Q tile once, pre-scaled by 1/sqrt(D)
    {
        const int r = tid >> 2, c = tid & 3;
        const float4* src = (const float4*)(qbase + (size_t)r * D_);
#pragma unroll
        for (int i = 0; i < 4; ++i) {
            float4 t4 = src[c * 4 + i];
            t4.x *= 0.125f; t4.y *= 0.125f; t4.z *= 0.125f; t4.w *= 0.125f;
            *(float4*)&Qs[r * LP + (c * 4 + i) * 4] = t4;
        }
    }

    float ctxa[4][4] = {};
    float mrow[4] = {-INFINITY, -INFINITY, -INFINITY, -INFINITY};
    float lrow[4] = {};

    const int ntiles = (NV + 63) >> 6;
    for (int tile = 0; tile < ntiles; ++tile) {
        __syncthreads();                    // prev readers of Ks/Vs done
        {
            const int r = tid >> 2, c = tid & 3;
            const int pos = tile * 64 + r;
            const int idx = list[pos < NV ? pos : 0];   // clamp: tail masked below
            const float4* ks = (const float4*)(kbase + (size_t)idx * D_);
            const float4* vs = (const float4*)(vbase + (size_t)idx * D_);
#pragma unroll
            for (int i = 0; i < 4; ++i) {
                *(float4*)&Ks[r * LP + (c * 4 + i) * 4] = ks[c * 4 + i];
                *(float4*)&Vs[r * LP + (c * 4 + i) * 4] = vs[c * 4 + i];
            }
        }
        __syncthreads();

        // ---- QK^T: 4x4 scores over d=64 ----
        float sr[4][4];
#pragma unroll
        for (int i = 0; i < 4; ++i)
#pragma unroll
            for (int j = 0; j < 4; ++j) sr[i][j] = 0.f;

#pragma unroll
        for (int d4 = 0; d4 < 16; ++d4) {
            float4 qv[4], kv[4];
#pragma unroll
            for (int i = 0; i < 4; ++i)
                qv[i] = *(const float4*)&Qs[(ty + 16 * i) * LP + d4 * 4];
#pragma unroll
            for (int j = 0; j < 4; ++j)
                kv[j] = *(const float4*)&Ks[(tx + 16 * j) * LP + d4 * 4];
#pragma unroll
            for (int i = 0; i < 4; ++i)
#pragma unroll
                for (int j = 0; j < 4; ++j)
                    sr[i][j] += qv[i].x * kv[j].x + qv[i].y * kv[j].y +
                                qv[i].z * kv[j].z + qv[i].w * kv[j].w;
        }

        // tail masking (keys beyond compacted count)
        const int kb = tile * 64;
#pragma unroll
        for (int j = 0; j < 4; ++j)
            if (kb + tx + 16 * j >= NV) {
#pragma unroll
                for (int i = 0; i < 4; ++i) sr[i][j] = -INFINITY;
            }

        // ---- online softmax (per q-row, across the 16 tx lanes) ----
#pragma unroll
        for (int i = 0; i < 4; ++i) {
            float mt = fmaxf(fmaxf(sr[i][0], sr[i][1]), fmaxf(sr[i][2], sr[i][3]));
            mt = fmaxf(mt, __shfl_xor(mt, 1, 16));
            mt = fmaxf(mt, __shfl_xor(mt, 2, 16));
            mt = fmaxf(mt, __shfl_xor(mt, 4, 16));
            mt = fmaxf(mt, __shfl_xor(mt, 8, 16));
            const float mn = fmaxf(mrow[i], mt);
            const float r = __expf(mrow[i] - mn);   // 0 on first tile
            mrow[i] = mn;
            float s = 0.f;
#pragma unroll
            for (int j = 0; j < 4; ++j) {
                sr[i][j] = __expf(sr[i][j] - mn);   // -inf -> 0
                s += sr[i][j];
            }
            s += __shfl_xor(s, 1, 16);
            s += __shfl_xor(s, 2, 16);
            s += __shfl_xor(s, 4, 16);
            s += __shfl_xor(s, 8, 16);
            lrow[i] = lrow[i] * r + s;
#pragma unroll
            for (int jd = 0; jd < 4; ++jd) ctxa[i][jd] *= r;
        }

        // ---- PV: ctx[q][d] += P[q][k] * V[k][d], P via shuffle broadcast ----
#pragma unroll
        for (int kk = 0; kk < 64; ++kk) {
            const int j = kk >> 4;
            const int src = kk & 15;
            const float4 vv = *(const float4*)&Vs[kk * LP + tx * 4];
            const float p0 = __shfl(sr[0][j], src, 16);
            const float p1 = __shfl(sr[1][j], src, 16);
            const float p2 = __shfl(sr[2][j], src, 16);
            const float p3 = __shfl(sr[3][j], src, 16);
            ctxa[0][0] += p0 * vv.x; ctxa[0][1] += p0 * vv.y; ctxa[0][2] += p0 * vv.z; ctxa[0][3] += p0 * vv.w;
            ctxa[1][0] += p1 * vv.x; ctxa[1][1] += p1 * vv.y; ctxa[1][2] += p1 * vv.z; ctxa[1][3] += p1 * vv.w;
            ctxa[2][0] += p2 * vv.x; ctxa[2][1] += p2 * vv.y; ctxa[2][2] += p2 * vv.z; ctxa[2][3] += p2 * vv.w;
            ctxa[3][0] += p3 * vv.x; ctxa[3][1] += p3 * vv.y; ctxa[3][2] += p3 * vv.z; ctxa[3][3] += p3 * vv.w;
        }
    }

    // ---- write normalized ctx ----
#pragma unroll
    for (int i = 0; i < 4; ++i) {
        const float inv = 1.f / lrow[i];
        const int t = qt * 64 + ty + 16 * i;
        float4 o;
        o.x = ctxa[i][0] * inv;
        o.y = ctxa[i][1] * inv;
        o.z = ctxa[i][2] * inv;
        o.w = ctxa[i][3] * inv;
        *(float4*)(ctx + ((size_t)(b * T_) + t) * C_ + h * D_ + tx * 4) = o;
    }
}

// ---------------------------------------------------------------------------
extern "C" void kernel_launch(void* const* d_in, const int* in_sizes, int n_in,
                              void* d_out, int out_size, void* d_ws, size_t ws_size,
                              hipStream_t stream) {
    const float* x    = (const float*)d_in[0];
    const int*   mask = (const int*)d_in[1];
    const int*   cdrs = (const int*)d_in[2];
    const float* Wq   = (const float*)d_in[3];
    const float* bq   = (const float*)d_in[4];
    const float* Wk   = (const float*)d_in[5];
    const float* bk   = (const float*)d_in[6];
    const float* Wv   = (const float*)d_in[7];
    const float* bv   = (const float*)d_in[8];
    const float* Wo   = (const float*)d_in[9];
    const float* bo   = (const float*)d_in[10];
    float* out = (float*)d_out;

    const size_t per = (size_t)B_ * H_ * T_ * D_;   // 4M floats
    float* qbuf   = (float*)d_ws;
    float* kbuf   = qbuf + per;
    float* vbuf   = kbuf + per;
    float* ctxbuf = vbuf + per;
    int*   klist  = (int*)(ctxbuf + (size_t)NROWS * C_);
    int*   kcnt   = klist + (size_t)B_ * 2 * T_;

    compact_kernel<<<B_, 256, 0, stream>>>(mask, cdrs, klist, kcnt);

    dim3 gqkv(NROWS / 64, C_ / 64, 3);
    gemm_qkv_kernel<<<gqkv, 256, 0, stream>>>(x, Wq, bq, Wk, bk, Wv, bv,
                                              qbuf, kbuf, vbuf);

    attn_kernel<<<dim3(T_ / 64, H_, B_), 256, 0, stream>>>(
        qbuf, kbuf, vbuf, klist, kcnt, ctxbuf);

    dim3 gout(NROWS / 64, C_ / 64, 1);
    gemm_out_kernel<<<gout, 256, 0, stream>>>(ctxbuf, Wo, bo, out);
}

// Round 3
// 435.486 us; speedup vs baseline: 2.6105x; 2.0651x over previous
//
#include <hip/hip_runtime.h>
#include <math.h>

#define B_ 4
#define T_ 2048
#define C_ 512
#define H_ 8
#define D_ 64
#define CDR_HEADS_ 2
#define NROWS (B_ * T_)          // 8192

typedef __bf16  bf16x8 __attribute__((ext_vector_type(8)));
typedef float   f32x4  __attribute__((ext_vector_type(4)));

#define MFMA16(a, b, c) __builtin_amdgcn_mfma_f32_16x16x32_bf16((a), (b), (c), 0, 0, 0)

static __device__ __forceinline__ unsigned short f2bf(float f) {
    unsigned u = __float_as_uint(f);
    u += 0x7FFF + ((u >> 16) & 1);          // RNE
    return (unsigned short)(u >> 16);
}

// ---------------------------------------------------------------------------
// Kernel 1: per-sample key-list compaction.
// listA (sel=0): keys with mask!=0                  -> heads 2..7
// listB (sel=1): mask!=0 && (any(cdrs)? cdrs!=0:1)  -> heads 0..1
// ---------------------------------------------------------------------------
__global__ __launch_bounds__(256) void compact_kernel(
    const int* __restrict__ mask, const int* __restrict__ cdrs,
    int* __restrict__ klist, int* __restrict__ kcnt) {
    __shared__ int s_any;
    __shared__ int sa[256], sb[256];
    const int b = blockIdx.x, tid = threadIdx.x;
    if (tid == 0) s_any = 0;
    __syncthreads();

    int m8[8], c8[8];
    int any = 0, ca = 0;
    const int base = b * T_ + tid * 8;
#pragma unroll
    for (int i = 0; i < 8; ++i) {
        m8[i] = mask[base + i];
        c8[i] = cdrs[base + i];
        any |= c8[i];
        ca += (m8[i] != 0);
    }
    if (any) s_any = 1;
    __syncthreads();
    const int en = s_any;

    int cb = 0;
#pragma unroll
    for (int i = 0; i < 8; ++i)
        cb += (m8[i] != 0 && (!en || c8[i] != 0));

    sa[tid] = ca; sb[tid] = cb;
    __syncthreads();
    for (int off = 1; off < 256; off <<= 1) {
        int va = 0, vb = 0;
        if (tid >= off) { va = sa[tid - off]; vb = sb[tid - off]; }
        __syncthreads();
        sa[tid] += va; sb[tid] += vb;
        __syncthreads();
    }

    int offA = sa[tid] - ca;
    int offB = sb[tid] - cb;
    int* la = klist + (size_t)(b * 2 + 0) * T_;
    int* lb = klist + (size_t)(b * 2 + 1) * T_;
#pragma unroll
    for (int i = 0; i < 8; ++i) {
        const int t = tid * 8 + i;
        if (m8[i] != 0) la[offA++] = t;
        if (m8[i] != 0 && (!en || c8[i] != 0)) lb[offB++] = t;
    }
    if (tid == 255) {
        kcnt[b * 2 + 0] = sa[255];
        kcnt[b * 2 + 1] = sb[255];
    }
}

// ---------------------------------------------------------------------------
// Tiled fp32 GEMM: out = A[M,C_] @ W[C_,C_] + bias.
// MODE 0: fp32 out, row-major [M, C_].
// MODE 1: bf16 out, heads layout [B,H,T,D], scaled by `scale`.
// ---------------------------------------------------------------------------
template <int MODE>
__device__ __forceinline__ void gemm_body(const float* __restrict__ A,
                                          const float* __restrict__ W,
                                          const float* __restrict__ bias,
                                          void* __restrict__ outp, float scale) {
    __shared__ float As[64][17];
    __shared__ float Bs[16][64];

    const int tid = threadIdx.x;
    const int tx = tid & 15;
    const int ty = tid >> 4;
    const int m0 = blockIdx.x * 64;
    const int n0 = blockIdx.y * 64;

    const int arow = tid >> 2;
    const int akq  = tid & 3;
    const int brow = tid >> 4;
    const int bnq  = tid & 15;

    float acc[4][4] = {};

    for (int k0 = 0; k0 < C_; k0 += 16) {
        float4 av = *(const float4*)(A + (size_t)(m0 + arow) * C_ + k0 + akq * 4);
        float4 bv = *(const float4*)(W + (size_t)(k0 + brow) * C_ + n0 + bnq * 4);
        As[arow][akq * 4 + 0] = av.x;
        As[arow][akq * 4 + 1] = av.y;
        As[arow][akq * 4 + 2] = av.z;
        As[arow][akq * 4 + 3] = av.w;
        *(float4*)&Bs[brow][bnq * 4] = bv;
        __syncthreads();
#pragma unroll
        for (int kk = 0; kk < 16; ++kk) {
            const float a0 = As[ty * 4 + 0][kk];
            const float a1 = As[ty * 4 + 1][kk];
            const float a2 = As[ty * 4 + 2][kk];
            const float a3 = As[ty * 4 + 3][kk];
            const float4 b4 = *(const float4*)&Bs[kk][tx * 4];
            acc[0][0] += a0 * b4.x; acc[0][1] += a0 * b4.y; acc[0][2] += a0 * b4.z; acc[0][3] += a0 * b4.w;
            acc[1][0] += a1 * b4.x; acc[1][1] += a1 * b4.y; acc[1][2] += a1 * b4.z; acc[1][3] += a1 * b4.w;
            acc[2][0] += a2 * b4.x; acc[2][1] += a2 * b4.y; acc[2][2] += a2 * b4.z; acc[2][3] += a2 * b4.w;
            acc[3][0] += a3 * b4.x; acc[3][1] += a3 * b4.y; acc[3][2] += a3 * b4.z; acc[3][3] += a3 * b4.w;
        }
        __syncthreads();
    }

    const float4 bb = *(const float4*)(bias + n0 + tx * 4);
#pragma unroll
    for (int i = 0; i < 4; ++i) {
        const int gm = m0 + ty * 4 + i;
        if (MODE == 0) {
            float* out = (float*)outp;
            float4 o;
            o.x = acc[i][0] + bb.x;
            o.y = acc[i][1] + bb.y;
            o.z = acc[i][2] + bb.z;
            o.w = acc[i][3] + bb.w;
            *(float4*)(out + (size_t)gm * C_ + n0 + tx * 4) = o;
        } else {
            unsigned short* out = (unsigned short*)outp;
            const int b = gm >> 11;
            const int t = gm & (T_ - 1);
            const int h = n0 >> 6;
            ushort4 o;
            o.x = f2bf((acc[i][0] + bb.x) * scale);
            o.y = f2bf((acc[i][1] + bb.y) * scale);
            o.z = f2bf((acc[i][2] + bb.z) * scale);
            o.w = f2bf((acc[i][3] + bb.w) * scale);
            *(ushort4*)(out + (((size_t)(b * H_ + h) * T_ + t) * D_) + tx * 4) = o;
        }
    }
}

__global__ __launch_bounds__(256) void gemm_qkv_kernel(
    const float* __restrict__ x,
    const float* __restrict__ Wq, const float* __restrict__ bq,
    const float* __restrict__ Wk, const float* __restrict__ bk,
    const float* __restrict__ Wv, const float* __restrict__ bv,
    unsigned short* __restrict__ q, unsigned short* __restrict__ k,
    unsigned short* __restrict__ v) {
    if (blockIdx.z == 0)      gemm_body<1>(x, Wq, bq, q, 0.125f);   // pre-scale Q
    else if (blockIdx.z == 1) gemm_body<1>(x, Wk, bk, k, 1.0f);
    else                      gemm_body<1>(x, Wv, bv, v, 1.0f);
}

__global__ __launch_bounds__(256) void gemm_out_kernel(
    const float* __restrict__ ctx, const float* __restrict__ Wo,
    const float* __restrict__ bo, float* __restrict__ out) {
    gemm_body<0>(ctx, Wo, bo, out, 1.0f);
}

// ---------------------------------------------------------------------------
// Kernel 2b: gather compacted K and transposed V into pre-swizzled 8KB tiles.
// Kc tile: element (i,d) at byte  i*128 + ((d>>3) ^ (i&7))*16 + (d&7)*2
// Vct tile: element (d,i) at byte d*128 + ((i>>3) ^ (d&7))*16 + (i&7)*2
// Zero-padded beyond NV.
// ---------------------------------------------------------------------------
__global__ __launch_bounds__(256) void gather_kernel(
    const unsigned short* __restrict__ Kb, const unsigned short* __restrict__ Vb,
    const int* __restrict__ klist, const int* __restrict__ kcnt,
    unsigned short* __restrict__ Kc, unsigned short* __restrict__ Vct) {
    __shared__ unsigned short Vs[64 * 72];
    const int tid = threadIdx.x;
    const int ti = blockIdx.x, h = blockIdx.y, b = blockIdx.z;
    const int sel = (h < CDR_HEADS_) ? 1 : 0;
    const int NV = kcnt[b * 2 + sel];
    if (ti * 64 >= NV) return;                       // block-uniform
    const int* __restrict__ list = klist + (size_t)(b * 2 + sel) * T_;
    const size_t bh = (size_t)b * H_ + h;
    const unsigned short* kb_ = Kb + bh * T_ * D_;
    const unsigned short* vb_ = Vb + bh * T_ * D_;
    unsigned short* kt = Kc + bh * (32 * 4096) + (size_t)ti * 4096;
    unsigned short* vt = Vct + bh * (32 * 4096) + (size_t)ti * 4096;

    const int i = tid >> 2, c = tid & 3;             // key-in-tile, 16-elem d-chunk
    const int pos = ti * 64 + i;
    int4 kv0 = {0,0,0,0}, kv1 = {0,0,0,0}, vv0 = {0,0,0,0}, vv1 = {0,0,0,0};
    if (pos < NV) {
        const int row = list[pos];
        const int4* kr = (const int4*)(kb_ + (size_t)row * D_ + c * 16);
        kv0 = kr[0]; kv1 = kr[1];
        const int4* vr = (const int4*)(vb_ + (size_t)row * D_ + c * 16);
        vv0 = vr[0]; vv1 = vr[1];
    }
    // K: swizzled direct store
    {
        const int s0 = (c * 2) ^ (i & 7), s1 = (c * 2 + 1) ^ (i & 7);
        *(int4*)(kt + i * 64 + s0 * 8) = kv0;
        *(int4*)(kt + i * 64 + s1 * 8) = kv1;
    }
    // V: stage row-major in LDS, then transposed+swizzled store
    *(int4*)(Vs + i * 72 + c * 16)     = vv0;
    *(int4*)(Vs + i * 72 + c * 16 + 8) = vv1;
    __syncthreads();
    {
        const int d = tid >> 2, c2 = tid & 3;        // d-row, 16-elem i-chunk
        union { unsigned short u[16]; int4 q[2]; } pk;
#pragma unroll
        for (int ii = 0; ii < 16; ++ii)
            pk.u[ii] = Vs[(c2 * 16 + ii) * 72 + d];
        const int s0 = (c2 * 2) ^ (d & 7), s1 = (c2 * 2 + 1) ^ (d & 7);
        *(int4*)(vt + d * 64 + s0 * 8) = pk.q[0];
        *(int4*)(vt + d * 64 + s1 * 8) = pk.q[1];
    }
}

// ---------------------------------------------------------------------------
// Kernel 3: bf16 MFMA flash attention over compacted, pre-swizzled tiles.
// Block: 128 q-rows, 4 waves (wave w owns rows w*32..w*32+31).
// Per tile (64 keys): 16 QK^T MFMAs + online softmax + 16 PV MFMAs per wave.
// ---------------------------------------------------------------------------
__global__ __launch_bounds__(256) void attn_mfma_kernel(
    const unsigned short* __restrict__ Qb, const unsigned short* __restrict__ Kc,
    const unsigned short* __restrict__ Vct, const int* __restrict__ kcnt,
    float* __restrict__ ctx) {
    __shared__ unsigned short Ks[4096];
    __shared__ unsigned short Vts[4096];
    __shared__ unsigned short Pl[4 * 32 * 72];       // per-wave P buffer, RS=144B

    const int tid = threadIdx.x;
    const int lane = tid & 63, w = tid >> 6;
    const int g = lane >> 4, l15 = lane & 15;
    const int qt = blockIdx.x, h = blockIdx.y, b = blockIdx.z;
    const int sel = (h < CDR_HEADS_) ? 1 : 0;
    const int NV = kcnt[b * 2 + sel];
    const int ntiles = (NV + 63) >> 6;
    const size_t bh = (size_t)b * H_ + h;
    const int swz = (l15 & 7) << 4;                  // byte-swizzle for B-frag reads

    // Q fragments in registers: aq[qb][kc], row = qb*16+l15, d = kc*32+g*8..+7
    bf16x8 aq[2][2];
    {
        const unsigned short* qp = Qb + (bh * T_ + (size_t)qt * 128 + w * 32) * D_;
#pragma unroll
        for (int qb = 0; qb < 2; ++qb)
#pragma unroll
            for (int kc = 0; kc < 2; ++kc) {
                int4 t4 = *(const int4*)(qp + (qb * 16 + l15) * D_ + kc * 32 + g * 8);
                aq[qb][kc] = __builtin_bit_cast(bf16x8, t4);
            }
    }

    f32x4 cacc[2][4];
#pragma unroll
    for (int qb = 0; qb < 2; ++qb)
#pragma unroll
        for (int db = 0; db < 4; ++db)
#pragma unroll
            for (int r = 0; r < 4; ++r) cacc[qb][db][r] = 0.f;
    float mr[2][4], lr[2][4];
#pragma unroll
    for (int qb = 0; qb < 2; ++qb)
#pragma unroll
        for (int r = 0; r < 4; ++r) { mr[qb][r] = -INFINITY; lr[qb][r] = 0.f; }

    const unsigned short* ktiles = Kc + bh * (32 * 4096);
    const unsigned short* vtiles = Vct + bh * (32 * 4096);
    unsigned short* Pw = Pl + w * (32 * 72);

    for (int t = 0; t < ntiles; ++t) {
        // ---- stage pre-swizzled 8KB tiles (linear copy via regs) ----
        const int4* gk = (const int4*)(ktiles + (size_t)t * 4096);
        const int4* gv = (const int4*)(vtiles + (size_t)t * 4096);
        int4 ka = gk[tid], kb2 = gk[tid + 256];
        int4 va = gv[tid], vb2 = gv[tid + 256];
        __syncthreads();
        ((int4*)Ks)[tid] = ka;  ((int4*)Ks)[tid + 256] = kb2;
        ((int4*)Vts)[tid] = va; ((int4*)Vts)[tid + 256] = vb2;
        __syncthreads();

        // ---- QK^T ----
        f32x4 s[2][4];
        const f32x4 z4 = {0.f, 0.f, 0.f, 0.f};
#pragma unroll
        for (int j = 0; j < 4; ++j) {
            const int rowb = (j * 16 + l15) * 128;
            bf16x8 bk0 = __builtin_bit_cast(bf16x8,
                *(const int4*)((const char*)Ks + ((rowb + g * 16) ^ swz)));
            bf16x8 bk1 = __builtin_bit_cast(bf16x8,
                *(const int4*)((const char*)Ks + ((rowb + 64 + g * 16) ^ swz)));
            s[0][j] = MFMA16(aq[0][0], bk0, z4);
            s[0][j] = MFMA16(aq[0][1], bk1, s[0][j]);
            s[1][j] = MFMA16(aq[1][0], bk0, z4);
            s[1][j] = MFMA16(aq[1][1], bk1, s[1][j]);
        }

        // ---- tail mask (cols >= NV) ----
        const int kb0 = t * 64;
#pragma unroll
        for (int j = 0; j < 4; ++j)
            if (kb0 + j * 16 + l15 >= NV) {
#pragma unroll
                for (int r = 0; r < 4; ++r) { s[0][j][r] = -INFINITY; s[1][j][r] = -INFINITY; }
            }

        // ---- online softmax: row q = qb*16 + g*4 + r, cols across l15 & j ----
#pragma unroll
        for (int qb = 0; qb < 2; ++qb)
#pragma unroll
            for (int r = 0; r < 4; ++r) {
                float mt = fmaxf(fmaxf(s[qb][0][r], s[qb][1][r]),
                                 fmaxf(s[qb][2][r], s[qb][3][r]));
                mt = fmaxf(mt, __shfl_xor(mt, 1, 16));
                mt = fmaxf(mt, __shfl_xor(mt, 2, 16));
                mt = fmaxf(mt, __shfl_xor(mt, 4, 16));
                mt = fmaxf(mt, __shfl_xor(mt, 8, 16));
                const float mn = fmaxf(mr[qb][r], mt);
                const float rr = __expf(mr[qb][r] - mn);    // 0 on first tile
                mr[qb][r] = mn;
                float sum = 0.f;
#pragma unroll
                for (int j = 0; j < 4; ++j) {
                    const float p = __expf(s[qb][j][r] - mn);
                    s[qb][j][r] = p;
                    sum += p;
                }
                sum += __shfl_xor(sum, 1, 16);
                sum += __shfl_xor(sum, 2, 16);
                sum += __shfl_xor(sum, 4, 16);
                sum += __shfl_xor(sum, 8, 16);
                lr[qb][r] = lr[qb][r] * rr + sum;
#pragma unroll
                for (int db = 0; db < 4; ++db) cacc[qb][db][r] *= rr;
            }

        // ---- P -> LDS (bf16), per-wave private region ----
#pragma unroll
        for (int qb = 0; qb < 2; ++qb)
#pragma unroll
            for (int j = 0; j < 4; ++j)
#pragma unroll
                for (int r = 0; r < 4; ++r)
                    Pw[(qb * 16 + g * 4 + r) * 72 + j * 16 + l15] = f2bf(s[qb][j][r]);

        // ---- PV ----
#pragma unroll
        for (int kc = 0; kc < 2; ++kc) {
            bf16x8 pa0 = __builtin_bit_cast(bf16x8,
                *(const int4*)(Pw + l15 * 72 + kc * 32 + g * 8));
            bf16x8 pa1 = __builtin_bit_cast(bf16x8,
                *(const int4*)(Pw + (16 + l15) * 72 + kc * 32 + g * 8));
#pragma unroll
            for (int db = 0; db < 4; ++db) {
                bf16x8 vb = __builtin_bit_cast(bf16x8,
                    *(const int4*)((const char*)Vts +
                        ((((db * 16 + l15) * 128) + kc * 64 + g * 16) ^ swz)));
                cacc[0][db] = MFMA16(pa0, vb, cacc[0][db]);
                cacc[1][db] = MFMA16(pa1, vb, cacc[1][db]);
            }
        }
    }

    // ---- epilogue: normalize + write fp32 ctx [B,T,C] ----
    const size_t trow = (size_t)b * T_ + (size_t)qt * 128 + w * 32;
#pragma unroll
    for (int qb = 0; qb < 2; ++qb)
#pragma unroll
        for (int r = 0; r < 4; ++r) {
            const float inv = 1.f / lr[qb][r];
            float* orow = ctx + (trow + qb * 16 + g * 4 + r) * C_ + h * D_;
#pragma unroll
            for (int db = 0; db < 4; ++db)
                orow[db * 16 + l15] = cacc[qb][db][r] * inv;
        }
}

// ---------------------------------------------------------------------------
extern "C" void kernel_launch(void* const* d_in, const int* in_sizes, int n_in,
                              void* d_out, int out_size, void* d_ws, size_t ws_size,
                              hipStream_t stream) {
    const float* x    = (const float*)d_in[0];
    const int*   mask = (const int*)d_in[1];
    const int*   cdrs = (const int*)d_in[2];
    const float* Wq   = (const float*)d_in[3];
    const float* bq   = (const float*)d_in[4];
    const float* Wk   = (const float*)d_in[5];
    const float* bk   = (const float*)d_in[6];
    const float* Wv   = (const float*)d_in[7];
    const float* bv   = (const float*)d_in[8];
    const float* Wo   = (const float*)d_in[9];
    const float* bo   = (const float*)d_in[10];
    float* out = (float*)d_out;

    const size_t per = (size_t)B_ * H_ * T_ * D_;    // 4M elements
    unsigned short* Qb  = (unsigned short*)d_ws;     // bf16, 8MB each
    unsigned short* Kb  = Qb + per;
    unsigned short* Vb  = Kb + per;
    unsigned short* Kc  = Vb + per;                  // 32 swizzled tiles per (b,h)
    unsigned short* Vct = Kc + per;
    float* ctxbuf = (float*)(Vct + per);             // fp32, 16MB
    int*   klist  = (int*)(ctxbuf + (size_t)NROWS * C_);
    int*   kcnt   = klist + (size_t)B_ * 2 * T_;

    compact_kernel<<<B_, 256, 0, stream>>>(mask, cdrs, klist, kcnt);

    dim3 gqkv(NROWS / 64, C_ / 64, 3);
    gemm_qkv_kernel<<<gqkv, 256, 0, stream>>>(x, Wq, bq, Wk, bk, Wv, bv,
                                              Qb, Kb, Vb);

    gather_kernel<<<dim3(32, H_, B_), 256, 0, stream>>>(Kb, Vb, klist, kcnt,
                                                        Kc, Vct);

    attn_mfma_kernel<<<dim3(T_ / 128, H_, B_), 256, 0, stream>>>(
        Qb, Kc, Vct, kcnt, ctxbuf);

    dim3 gout(NROWS / 64, C_ / 64, 1);
    gemm_out_kernel<<<gout, 256, 0, stream>>>(ctxbuf, Wo, bo, out);
}

// Round 4
// 243.263 us; speedup vs baseline: 4.6733x; 1.7902x over previous
//
#include <hip/hip_runtime.h>
#include <math.h>

#define B_ 4
#define T_ 2048
#define C_ 512
#define H_ 8
#define D_ 64
#define CDR_HEADS_ 2
#define NROWS (B_ * T_)          // 8192

typedef unsigned short ush;
typedef __bf16  bf16x8 __attribute__((ext_vector_type(8)));
typedef float   f32x4  __attribute__((ext_vector_type(4)));

#define MFMA16(a, b, c) __builtin_amdgcn_mfma_f32_16x16x32_bf16((a), (b), (c), 0, 0, 0)

static __device__ __forceinline__ ush f2bf(float f) {
    unsigned u = __float_as_uint(f);
    u += 0x7FFF + ((u >> 16) & 1);          // RNE
    return (ush)(u >> 16);
}
static __device__ __forceinline__ float bf2f(ush h) {
    return __uint_as_float(((unsigned)h) << 16);
}

// async 16B global->LDS (wave-uniform LDS base + lane*16, per-lane global src)
static __device__ __forceinline__ void gload16(const void* gsrc, void* ldst) {
    __builtin_amdgcn_global_load_lds(
        (const __attribute__((address_space(1))) unsigned int*)gsrc,
        (__attribute__((address_space(3))) unsigned int*)ldst, 16, 0, 0);
}

// ---------------------------------------------------------------------------
// Kernel 1: per-sample key-list compaction (unchanged).
// ---------------------------------------------------------------------------
__global__ __launch_bounds__(256) void compact_kernel(
    const int* __restrict__ mask, const int* __restrict__ cdrs,
    int* __restrict__ klist, int* __restrict__ kcnt) {
    __shared__ int s_any;
    __shared__ int sa[256], sb[256];
    const int b = blockIdx.x, tid = threadIdx.x;
    if (tid == 0) s_any = 0;
    __syncthreads();

    int m8[8], c8[8];
    int any = 0, ca = 0;
    const int base = b * T_ + tid * 8;
#pragma unroll
    for (int i = 0; i < 8; ++i) {
        m8[i] = mask[base + i];
        c8[i] = cdrs[base + i];
        any |= c8[i];
        ca += (m8[i] != 0);
    }
    if (any) s_any = 1;
    __syncthreads();
    const int en = s_any;

    int cb = 0;
#pragma unroll
    for (int i = 0; i < 8; ++i)
        cb += (m8[i] != 0 && (!en || c8[i] != 0));

    sa[tid] = ca; sb[tid] = cb;
    __syncthreads();
    for (int off = 1; off < 256; off <<= 1) {
        int va = 0, vb = 0;
        if (tid >= off) { va = sa[tid - off]; vb = sb[tid - off]; }
        __syncthreads();
        sa[tid] += va; sb[tid] += vb;
        __syncthreads();
    }

    int offA = sa[tid] - ca;
    int offB = sb[tid] - cb;
    int* la = klist + (size_t)(b * 2 + 0) * T_;
    int* lb = klist + (size_t)(b * 2 + 1) * T_;
#pragma unroll
    for (int i = 0; i < 8; ++i) {
        const int t = tid * 8 + i;
        if (m8[i] != 0) la[offA++] = t;
        if (m8[i] != 0 && (!en || c8[i] != 0)) lb[offB++] = t;
    }
    if (tid == 255) {
        kcnt[b * 2 + 0] = sa[255];
        kcnt[b * 2 + 1] = sb[255];
    }
}

// ---------------------------------------------------------------------------
// Prep: decompose fp32 matrix [8192][512] into hi/lo bf16 TILED-SWIZZLED.
// Tile (mt,kt): 128x32 bf16 (8KB), base elems (mt*16+kt)*4096.
// Element (ml,kl) at byte ml*64 + ((kl>>3) ^ ((ml>>1)&3))*16 + (kl&7)*2.
// ---------------------------------------------------------------------------
__global__ __launch_bounds__(256) void decomp_a_kernel(
    const float* __restrict__ src, ush* __restrict__ Dh, ush* __restrict__ Dl) {
    const int id = blockIdx.x * 256 + threadIdx.x;   // 0..524287
    const int m = id >> 6, kc = id & 63;             // row, 8-elem chunk
    const float* p = src + (size_t)m * C_ + kc * 8;
    const float4 a = ((const float4*)p)[0];
    const float4 b2 = ((const float4*)p)[1];
    float xv[8] = {a.x, a.y, a.z, a.w, b2.x, b2.y, b2.z, b2.w};
    union { ush u[8]; int4 q; } hi, lo;
#pragma unroll
    for (int i = 0; i < 8; ++i) {
        const ush h = f2bf(xv[i]);
        hi.u[i] = h;
        lo.u[i] = f2bf(xv[i] - bf2f(h));
    }
    const int mt = m >> 7, ml = m & 127, kt = kc >> 2, cidx = kc & 3;
    const size_t tbase = ((size_t)mt * 16 + kt) * 4096;
    const int boff = ml * 64 + ((cidx ^ ((ml >> 1) & 3)) << 4);
    *(int4*)((char*)(Dh + tbase) + boff) = hi.q;
    *(int4*)((char*)(Dl + tbase) + boff) = lo.q;
}

// ---------------------------------------------------------------------------
// Prep: transpose + decompose W [K=512][N=512] -> Wt hi/lo tiled-swizzled.
// Per matrix: tiles (nt,kt), element (nl,kl) as above (nl = n-local row).
// 4 matrices (Wq,Wk,Wv,Wo) at mat*262144 elem offsets.
// ---------------------------------------------------------------------------
__global__ __launch_bounds__(256) void decomp_w_kernel(
    const float* __restrict__ W0, const float* __restrict__ W1,
    const float* __restrict__ W2, const float* __restrict__ W3,
    ush* __restrict__ Wth, ush* __restrict__ Wtl) {
    const int mat = blockIdx.y;
    const float* W = (mat == 0) ? W0 : (mat == 1) ? W1 : (mat == 2) ? W2 : W3;
    const int id = blockIdx.x * 256 + threadIdx.x;   // 0..32767
    const int n = id & 511, kc = id >> 9;            // col, 8-elem k-chunk
    float xv[8];
#pragma unroll
    for (int j = 0; j < 8; ++j)
        xv[j] = W[(size_t)(kc * 8 + j) * C_ + n];
    union { ush u[8]; int4 q; } hi, lo;
#pragma unroll
    for (int i = 0; i < 8; ++i) {
        const ush h = f2bf(xv[i]);
        hi.u[i] = h;
        lo.u[i] = f2bf(xv[i] - bf2f(h));
    }
    const int nt = n >> 7, nl = n & 127, kt = kc >> 2, cidx = kc & 3;
    const size_t tbase = (size_t)mat * 262144 + ((size_t)nt * 16 + kt) * 4096;
    const int boff = nl * 64 + ((cidx ^ ((nl >> 1) & 3)) << 4);
    *(int4*)((char*)(Wth + tbase) + boff) = hi.q;
    *(int4*)((char*)(Wtl + tbase) + boff) = lo.q;
}

// ---------------------------------------------------------------------------
// bf16x3-split MFMA GEMM: C = A@W + bias, fp32-class accuracy.
// A tiles: Ah/Al [64 mt][16 kt]; W^T tiles: Bh/Bl [4 nt][16 kt].
// Block: 128x128 out tile, 4 waves (2x2 quadrants of 64x64).
// OUTMODE 0: fp32 row-major [M,C_]. OUTMODE 1: bf16 heads [B,H,T,D] * scale.
// ---------------------------------------------------------------------------
template <int OUTMODE>
static __device__ __forceinline__ void gemm3_body(
    const ush* __restrict__ Ah_g, const ush* __restrict__ Al_g,
    const ush* __restrict__ Bh_g, const ush* __restrict__ Bl_g,
    const float* __restrict__ bias, void* __restrict__ outp, float scale) {
    __shared__ char lds[32768];                      // Ah|Al|Bh|Bl, 8KB each
    char* const sAh = lds;
    char* const sAl = lds + 8192;
    char* const sBh = lds + 16384;
    char* const sBl = lds + 24576;

    const int tid = threadIdx.x;
    const int lane = tid & 63, w = tid >> 6;
    const int g = lane >> 4, l15 = lane & 15;
    const int wr = w >> 1, wc = w & 1;
    const int mt = blockIdx.x, nt = blockIdx.y;

    const char* gAh = (const char*)Ah_g + (size_t)(mt * 16) * 8192;
    const char* gAl = (const char*)Al_g + (size_t)(mt * 16) * 8192;
    const char* gBh = (const char*)Bh_g + (size_t)(nt * 16) * 8192;
    const char* gBl = (const char*)Bl_g + (size_t)(nt * 16) * 8192;

    f32x4 acc[4][4];
#pragma unroll
    for (int i = 0; i < 4; ++i)
#pragma unroll
        for (int j = 0; j < 4; ++j)
#pragma unroll
            for (int r = 0; r < 4; ++r) acc[i][j][r] = 0.f;

    const int lw = w * 2048;                         // wave's LDS segment
    for (int kt = 0; kt < 16; ++kt) {
        __syncthreads();                             // prev compute done
        const size_t gb = (size_t)kt * 8192 + lw + lane * 16;
        gload16(gAh + gb,        sAh + lw);
        gload16(gAh + gb + 1024, sAh + lw + 1024);
        gload16(gAl + gb,        sAl + lw);
        gload16(gAl + gb + 1024, sAl + lw + 1024);
        gload16(gBh + gb,        sBh + lw);
        gload16(gBh + gb + 1024, sBh + lw + 1024);
        gload16(gBl + gb,        sBl + lw);
        gload16(gBl + gb + 1024, sBl + lw + 1024);
        __syncthreads();                             // vmcnt(0) drained here

        bf16x8 fah[4], fal[4], fbh[4], fbl[4];
#pragma unroll
        for (int rb = 0; rb < 4; ++rb) {
            const int row = wr * 64 + rb * 16 + l15;
            const int off = row * 64 + ((g ^ ((row >> 1) & 3)) << 4);
            fah[rb] = __builtin_bit_cast(bf16x8, *(const int4*)(sAh + off));
            fal[rb] = __builtin_bit_cast(bf16x8, *(const int4*)(sAl + off));
        }
#pragma unroll
        for (int cb = 0; cb < 4; ++cb) {
            const int row = wc * 64 + cb * 16 + l15;
            const int off = row * 64 + ((g ^ ((row >> 1) & 3)) << 4);
            fbh[cb] = __builtin_bit_cast(bf16x8, *(const int4*)(sBh + off));
            fbl[cb] = __builtin_bit_cast(bf16x8, *(const int4*)(sBl + off));
        }
#pragma unroll
        for (int rb = 0; rb < 4; ++rb)
#pragma unroll
            for (int cb = 0; cb < 4; ++cb) {
                acc[rb][cb] = MFMA16(fah[rb], fbh[cb], acc[rb][cb]);
                acc[rb][cb] = MFMA16(fah[rb], fbl[cb], acc[rb][cb]);
                acc[rb][cb] = MFMA16(fal[rb], fbh[cb], acc[rb][cb]);
            }
    }

    // epilogue
    const int mbase = mt * 128 + wr * 64;
    const int nbase = nt * 128 + wc * 64;
    float bcol[4];
#pragma unroll
    for (int cb = 0; cb < 4; ++cb) bcol[cb] = bias[nbase + cb * 16 + l15];

#pragma unroll
    for (int rb = 0; rb < 4; ++rb)
#pragma unroll
        for (int cb = 0; cb < 4; ++cb) {
            const int colg = nbase + cb * 16 + l15;
#pragma unroll
            for (int r = 0; r < 4; ++r) {
                const int m = mbase + rb * 16 + g * 4 + r;
                const float vv = acc[rb][cb][r] + bcol[cb];
                if (OUTMODE == 0) {
                    ((float*)outp)[(size_t)m * C_ + colg] = vv;
                } else {
                    const int bb = m >> 11, t = m & (T_ - 1);
                    const int h = colg >> 6, d = colg & 63;
                    ((ush*)outp)[(((size_t)(bb * H_ + h) * T_ + t) * D_) + d] =
                        f2bf(vv * scale);
                }
            }
        }
}

__global__ __launch_bounds__(256) void gemm3_qkv_kernel(
    const ush* __restrict__ Xh, const ush* __restrict__ Xl,
    const ush* __restrict__ Wth, const ush* __restrict__ Wtl,
    const float* __restrict__ bq, const float* __restrict__ bk,
    const float* __restrict__ bv,
    ush* __restrict__ Qb, ush* __restrict__ Kb, ush* __restrict__ Vb) {
    const int z = blockIdx.z;
    const ush* bh = Wth + (size_t)z * 262144;
    const ush* bl = Wtl + (size_t)z * 262144;
    if (z == 0)      gemm3_body<1>(Xh, Xl, bh, bl, bq, Qb, 0.125f);  // Q pre-scaled
    else if (z == 1) gemm3_body<1>(Xh, Xl, bh, bl, bk, Kb, 1.0f);
    else             gemm3_body<1>(Xh, Xl, bh, bl, bv, Vb, 1.0f);
}

__global__ __launch_bounds__(256) void gemm3_out_kernel(
    const ush* __restrict__ Ch, const ush* __restrict__ Cl,
    const ush* __restrict__ Wth, const ush* __restrict__ Wtl,
    const float* __restrict__ bo, float* __restrict__ out) {
    gemm3_body<0>(Ch, Cl, Wth + (size_t)3 * 262144, Wtl + (size_t)3 * 262144,
                  bo, out, 1.0f);
}

// ---------------------------------------------------------------------------
// Gather compacted K / transposed V into pre-swizzled 8KB tiles (unchanged).
// ---------------------------------------------------------------------------
__global__ __launch_bounds__(256) void gather_kernel(
    const ush* __restrict__ Kb, const ush* __restrict__ Vb,
    const int* __restrict__ klist, const int* __restrict__ kcnt,
    ush* __restrict__ Kc, ush* __restrict__ Vct) {
    __shared__ ush Vs[64 * 72];
    const int tid = threadIdx.x;
    const int ti = blockIdx.x, h = blockIdx.y, b = blockIdx.z;
    const int sel = (h < CDR_HEADS_) ? 1 : 0;
    const int NV = kcnt[b * 2 + sel];
    if (ti * 64 >= NV) return;
    const int* __restrict__ list = klist + (size_t)(b * 2 + sel) * T_;
    const size_t bh = (size_t)b * H_ + h;
    const ush* kb_ = Kb + bh * T_ * D_;
    const ush* vb_ = Vb + bh * T_ * D_;
    ush* kt = Kc + bh * (32 * 4096) + (size_t)ti * 4096;
    ush* vt = Vct + bh * (32 * 4096) + (size_t)ti * 4096;

    const int i = tid >> 2, c = tid & 3;
    const int pos = ti * 64 + i;
    int4 kv0 = {0,0,0,0}, kv1 = {0,0,0,0}, vv0 = {0,0,0,0}, vv1 = {0,0,0,0};
    if (pos < NV) {
        const int row = list[pos];
        const int4* kr = (const int4*)(kb_ + (size_t)row * D_ + c * 16);
        kv0 = kr[0]; kv1 = kr[1];
        const int4* vr = (const int4*)(vb_ + (size_t)row * D_ + c * 16);
        vv0 = vr[0]; vv1 = vr[1];
    }
    {
        const int s0 = (c * 2) ^ (i & 7), s1 = (c * 2 + 1) ^ (i & 7);
        *(int4*)(kt + i * 64 + s0 * 8) = kv0;
        *(int4*)(kt + i * 64 + s1 * 8) = kv1;
    }
    *(int4*)(Vs + i * 72 + c * 16)     = vv0;
    *(int4*)(Vs + i * 72 + c * 16 + 8) = vv1;
    __syncthreads();
    {
        const int d = tid >> 2, c2 = tid & 3;
        union { ush u[16]; int4 q[2]; } pk;
#pragma unroll
        for (int ii = 0; ii < 16; ++ii)
            pk.u[ii] = Vs[(c2 * 16 + ii) * 72 + d];
        const int s0 = (c2 * 2) ^ (d & 7), s1 = (c2 * 2 + 1) ^ (d & 7);
        *(int4*)(vt + d * 64 + s0 * 8) = pk.q[0];
        *(int4*)(vt + d * 64 + s1 * 8) = pk.q[1];
    }
}

// ---------------------------------------------------------------------------
// bf16 MFMA flash attention (unchanged from R2).
// ---------------------------------------------------------------------------
__global__ __launch_bounds__(256) void attn_mfma_kernel(
    const ush* __restrict__ Qb, const ush* __restrict__ Kc,
    const ush* __restrict__ Vct, const int* __restrict__ kcnt,
    float* __restrict__ ctx) {
    __shared__ ush Ks[4096];
    __shared__ ush Vts[4096];
    __shared__ ush Pl[4 * 32 * 72];

    const int tid = threadIdx.x;
    const int lane = tid & 63, w = tid >> 6;
    const int g = lane >> 4, l15 = lane & 15;
    const int qt = blockIdx.x, h = blockIdx.y, b = blockIdx.z;
    const int sel = (h < CDR_HEADS_) ? 1 : 0;
    const int NV = kcnt[b * 2 + sel];
    const int ntiles = (NV + 63) >> 6;
    const size_t bh = (size_t)b * H_ + h;
    const int swz = (l15 & 7) << 4;

    bf16x8 aq[2][2];
    {
        const ush* qp = Qb + (bh * T_ + (size_t)qt * 128 + w * 32) * D_;
#pragma unroll
        for (int qb = 0; qb < 2; ++qb)
#pragma unroll
            for (int kc = 0; kc < 2; ++kc) {
                int4 t4 = *(const int4*)(qp + (qb * 16 + l15) * D_ + kc * 32 + g * 8);
                aq[qb][kc] = __builtin_bit_cast(bf16x8, t4);
            }
    }

    f32x4 cacc[2][4];
#pragma unroll
    for (int qb = 0; qb < 2; ++qb)
#pragma unroll
        for (int db = 0; db < 4; ++db)
#pragma unroll
            for (int r = 0; r < 4; ++r) cacc[qb][db][r] = 0.f;
    float mr[2][4], lr[2][4];
#pragma unroll
    for (int qb = 0; qb < 2; ++qb)
#pragma unroll
        for (int r = 0; r < 4; ++r) { mr[qb][r] = -INFINITY; lr[qb][r] = 0.f; }

    const ush* ktiles = Kc + bh * (32 * 4096);
    const ush* vtiles = Vct + bh * (32 * 4096);
    ush* Pw = Pl + w * (32 * 72);

    for (int t = 0; t < ntiles; ++t) {
        const int4* gk = (const int4*)(ktiles + (size_t)t * 4096);
        const int4* gv = (const int4*)(vtiles + (size_t)t * 4096);
        int4 ka = gk[tid], kb2 = gk[tid + 256];
        int4 va = gv[tid], vb2 = gv[tid + 256];
        __syncthreads();
        ((int4*)Ks)[tid] = ka;  ((int4*)Ks)[tid + 256] = kb2;
        ((int4*)Vts)[tid] = va; ((int4*)Vts)[tid + 256] = vb2;
        __syncthreads();

        f32x4 s[2][4];
        const f32x4 z4 = {0.f, 0.f, 0.f, 0.f};
#pragma unroll
        for (int j = 0; j < 4; ++j) {
            const int rowb = (j * 16 + l15) * 128;
            bf16x8 bk0 = __builtin_bit_cast(bf16x8,
                *(const int4*)((const char*)Ks + ((rowb + g * 16) ^ swz)));
            bf16x8 bk1 = __builtin_bit_cast(bf16x8,
                *(const int4*)((const char*)Ks + ((rowb + 64 + g * 16) ^ swz)));
            s[0][j] = MFMA16(aq[0][0], bk0, z4);
            s[0][j] = MFMA16(aq[0][1], bk1, s[0][j]);
            s[1][j] = MFMA16(aq[1][0], bk0, z4);
            s[1][j] = MFMA16(aq[1][1], bk1, s[1][j]);
        }

        const int kb0 = t * 64;
#pragma unroll
        for (int j = 0; j < 4; ++j)
            if (kb0 + j * 16 + l15 >= NV) {
#pragma unroll
                for (int r = 0; r < 4; ++r) { s[0][j][r] = -INFINITY; s[1][j][r] = -INFINITY; }
            }

#pragma unroll
        for (int qb = 0; qb < 2; ++qb)
#pragma unroll
            for (int r = 0; r < 4; ++r) {
                float mt = fmaxf(fmaxf(s[qb][0][r], s[qb][1][r]),
                                 fmaxf(s[qb][2][r], s[qb][3][r]));
                mt = fmaxf(mt, __shfl_xor(mt, 1, 16));
                mt = fmaxf(mt, __shfl_xor(mt, 2, 16));
                mt = fmaxf(mt, __shfl_xor(mt, 4, 16));
                mt = fmaxf(mt, __shfl_xor(mt, 8, 16));
                const float mn = fmaxf(mr[qb][r], mt);
                const float rr = __expf(mr[qb][r] - mn);
                mr[qb][r] = mn;
                float sum = 0.f;
#pragma unroll
                for (int j = 0; j < 4; ++j) {
                    const float p = __expf(s[qb][j][r] - mn);
                    s[qb][j][r] = p;
                    sum += p;
                }
                sum += __shfl_xor(sum, 1, 16);
                sum += __shfl_xor(sum, 2, 16);
                sum += __shfl_xor(sum, 4, 16);
                sum += __shfl_xor(sum, 8, 16);
                lr[qb][r] = lr[qb][r] * rr + sum;
#pragma unroll
                for (int db = 0; db < 4; ++db) cacc[qb][db][r] *= rr;
            }

#pragma unroll
        for (int qb = 0; qb < 2; ++qb)
#pragma unroll
            for (int j = 0; j < 4; ++j)
#pragma unroll
                for (int r = 0; r < 4; ++r)
                    Pw[(qb * 16 + g * 4 + r) * 72 + j * 16 + l15] = f2bf(s[qb][j][r]);

#pragma unroll
        for (int kc = 0; kc < 2; ++kc) {
            bf16x8 pa0 = __builtin_bit_cast(bf16x8,
                *(const int4*)(Pw + l15 * 72 + kc * 32 + g * 8));
            bf16x8 pa1 = __builtin_bit_cast(bf16x8,
                *(const int4*)(Pw + (16 + l15) * 72 + kc * 32 + g * 8));
#pragma unroll
            for (int db = 0; db < 4; ++db) {
                bf16x8 vb = __builtin_bit_cast(bf16x8,
                    *(const int4*)((const char*)Vts +
                        ((((db * 16 + l15) * 128) + kc * 64 + g * 16) ^ swz)));
                cacc[0][db] = MFMA16(pa0, vb, cacc[0][db]);
                cacc[1][db] = MFMA16(pa1, vb, cacc[1][db]);
            }
        }
    }

    const size_t trow = (size_t)b * T_ + (size_t)qt * 128 + w * 32;
#pragma unroll
    for (int qb = 0; qb < 2; ++qb)
#pragma unroll
        for (int r = 0; r < 4; ++r) {
            const float inv = 1.f / lr[qb][r];
            float* orow = ctx + (trow + qb * 16 + g * 4 + r) * C_ + h * D_;
#pragma unroll
            for (int db = 0; db < 4; ++db)
                orow[db * 16 + l15] = cacc[qb][db][r] * inv;
        }
}

// ---------------------------------------------------------------------------
extern "C" void kernel_launch(void* const* d_in, const int* in_sizes, int n_in,
                              void* d_out, int out_size, void* d_ws, size_t ws_size,
                              hipStream_t stream) {
    const float* x    = (const float*)d_in[0];
    const int*   mask = (const int*)d_in[1];
    const int*   cdrs = (const int*)d_in[2];
    const float* Wq   = (const float*)d_in[3];
    const float* bq   = (const float*)d_in[4];
    const float* Wk   = (const float*)d_in[5];
    const float* bk   = (const float*)d_in[6];
    const float* Wv   = (const float*)d_in[7];
    const float* bv   = (const float*)d_in[8];
    const float* Wo   = (const float*)d_in[9];
    const float* bo   = (const float*)d_in[10];
    float* out = (float*)d_out;

    const size_t per = (size_t)B_ * H_ * T_ * D_;    // 4M elements
    ush* Qb  = (ush*)d_ws;                           // bf16 [B,H,T,D]
    ush* Kb  = Qb + per;
    ush* Vb  = Kb + per;
    ush* Kc  = Vb + per;                             // swizzled K tiles
    ush* Vct = Kc + per;                             // swizzled V^T tiles
    ush* Xh  = Vct + per;                            // x / ctx hi tiles
    ush* Xl  = Xh + per;                             // x / ctx lo tiles
    ush* Wth = Xl + per;                             // 4 matrices W^T hi
    ush* Wtl = Wth + 4 * 262144;                     // 4 matrices W^T lo
    int* klist = (int*)(Wtl + 4 * 262144);
    int* kcnt  = klist + (size_t)B_ * 2 * T_;
    float* ctxf = (float*)Kb;                        // aliases Kb+Vb (dead after gather)

    compact_kernel<<<B_, 256, 0, stream>>>(mask, cdrs, klist, kcnt);

    decomp_a_kernel<<<2048, 256, 0, stream>>>(x, Xh, Xl);
    decomp_w_kernel<<<dim3(128, 4), 256, 0, stream>>>(Wq, Wk, Wv, Wo, Wth, Wtl);

    gemm3_qkv_kernel<<<dim3(64, 4, 3), 256, 0, stream>>>(
        Xh, Xl, Wth, Wtl, bq, bk, bv, Qb, Kb, Vb);

    gather_kernel<<<dim3(32, H_, B_), 256, 0, stream>>>(Kb, Vb, klist, kcnt,
                                                        Kc, Vct);

    attn_mfma_kernel<<<dim3(T_ / 128, H_, B_), 256, 0, stream>>>(
        Qb, Kc, Vct, kcnt, ctxf);

    decomp_a_kernel<<<2048, 256, 0, stream>>>(ctxf, Xh, Xl);

    gemm3_out_kernel<<<dim3(64, 4), 256, 0, stream>>>(Xh, Xl, Wth, Wtl, bo, out);
}

// Round 5
// 222.886 us; speedup vs baseline: 5.1005x; 1.0914x over previous
//
#include <hip/hip_runtime.h>
#include <math.h>

#define B_ 4
#define T_ 2048
#define C_ 512
#define H_ 8
#define D_ 64
#define CDR_HEADS_ 2
#define NROWS (B_ * T_)          // 8192

typedef unsigned short ush;
typedef __bf16  bf16x8 __attribute__((ext_vector_type(8)));
typedef float   f32x4  __attribute__((ext_vector_type(4)));

#define MFMA16(a, b, c) __builtin_amdgcn_mfma_f32_16x16x32_bf16((a), (b), (c), 0, 0, 0)

static __device__ __forceinline__ ush f2bf(float f) {
    unsigned u = __float_as_uint(f);
    u += 0x7FFF + ((u >> 16) & 1);          // RNE
    return (ush)(u >> 16);
}
static __device__ __forceinline__ float bf2f(ush h) {
    return __uint_as_float(((unsigned)h) << 16);
}

// async 16B global->LDS (wave-uniform LDS base + lane*16, per-lane global src)
static __device__ __forceinline__ void gload16(const void* gsrc, void* ldst) {
    __builtin_amdgcn_global_load_lds(
        (const __attribute__((address_space(1))) unsigned int*)gsrc,
        (__attribute__((address_space(3))) unsigned int*)ldst, 16, 0, 0);
}

// ---------------------------------------------------------------------------
// Kernel 1: per-sample key-list compaction (unchanged).
// ---------------------------------------------------------------------------
__global__ __launch_bounds__(256) void compact_kernel(
    const int* __restrict__ mask, const int* __restrict__ cdrs,
    int* __restrict__ klist, int* __restrict__ kcnt) {
    __shared__ int s_any;
    __shared__ int sa[256], sb[256];
    const int b = blockIdx.x, tid = threadIdx.x;
    if (tid == 0) s_any = 0;
    __syncthreads();

    int m8[8], c8[8];
    int any = 0, ca = 0;
    const int base = b * T_ + tid * 8;
#pragma unroll
    for (int i = 0; i < 8; ++i) {
        m8[i] = mask[base + i];
        c8[i] = cdrs[base + i];
        any |= c8[i];
        ca += (m8[i] != 0);
    }
    if (any) s_any = 1;
    __syncthreads();
    const int en = s_any;

    int cb = 0;
#pragma unroll
    for (int i = 0; i < 8; ++i)
        cb += (m8[i] != 0 && (!en || c8[i] != 0));

    sa[tid] = ca; sb[tid] = cb;
    __syncthreads();
    for (int off = 1; off < 256; off <<= 1) {
        int va = 0, vb = 0;
        if (tid >= off) { va = sa[tid - off]; vb = sb[tid - off]; }
        __syncthreads();
        sa[tid] += va; sb[tid] += vb;
        __syncthreads();
    }

    int offA = sa[tid] - ca;
    int offB = sb[tid] - cb;
    int* la = klist + (size_t)(b * 2 + 0) * T_;
    int* lb = klist + (size_t)(b * 2 + 1) * T_;
#pragma unroll
    for (int i = 0; i < 8; ++i) {
        const int t = tid * 8 + i;
        if (m8[i] != 0) la[offA++] = t;
        if (m8[i] != 0 && (!en || c8[i] != 0)) lb[offB++] = t;
    }
    if (tid == 255) {
        kcnt[b * 2 + 0] = sa[255];
        kcnt[b * 2 + 1] = sb[255];
    }
}

// ---------------------------------------------------------------------------
// Prep: decompose fp32 matrix [8192][512] into hi/lo bf16 TILED-SWIZZLED.
// ---------------------------------------------------------------------------
__global__ __launch_bounds__(256) void decomp_a_kernel(
    const float* __restrict__ src, ush* __restrict__ Dh, ush* __restrict__ Dl) {
    const int id = blockIdx.x * 256 + threadIdx.x;   // 0..524287
    const int m = id >> 6, kc = id & 63;             // row, 8-elem chunk
    const float* p = src + (size_t)m * C_ + kc * 8;
    const float4 a = ((const float4*)p)[0];
    const float4 b2 = ((const float4*)p)[1];
    float xv[8] = {a.x, a.y, a.z, a.w, b2.x, b2.y, b2.z, b2.w};
    union { ush u[8]; int4 q; } hi, lo;
#pragma unroll
    for (int i = 0; i < 8; ++i) {
        const ush h = f2bf(xv[i]);
        hi.u[i] = h;
        lo.u[i] = f2bf(xv[i] - bf2f(h));
    }
    const int mt = m >> 7, ml = m & 127, kt = kc >> 2, cidx = kc & 3;
    const size_t tbase = ((size_t)mt * 16 + kt) * 4096;
    const int boff = ml * 64 + ((cidx ^ ((ml >> 1) & 3)) << 4);
    *(int4*)((char*)(Dh + tbase) + boff) = hi.q;
    *(int4*)((char*)(Dl + tbase) + boff) = lo.q;
}

// ---------------------------------------------------------------------------
// Prep: transpose + decompose W [K=512][N=512] -> Wt hi/lo tiled-swizzled.
// ---------------------------------------------------------------------------
__global__ __launch_bounds__(256) void decomp_w_kernel(
    const float* __restrict__ W0, const float* __restrict__ W1,
    const float* __restrict__ W2, const float* __restrict__ W3,
    ush* __restrict__ Wth, ush* __restrict__ Wtl) {
    const int mat = blockIdx.y;
    const float* W = (mat == 0) ? W0 : (mat == 1) ? W1 : (mat == 2) ? W2 : W3;
    const int id = blockIdx.x * 256 + threadIdx.x;   // 0..32767
    const int n = id & 511, kc = id >> 9;            // col, 8-elem k-chunk
    float xv[8];
#pragma unroll
    for (int j = 0; j < 8; ++j)
        xv[j] = W[(size_t)(kc * 8 + j) * C_ + n];
    union { ush u[8]; int4 q; } hi, lo;
#pragma unroll
    for (int i = 0; i < 8; ++i) {
        const ush h = f2bf(xv[i]);
        hi.u[i] = h;
        lo.u[i] = f2bf(xv[i] - bf2f(h));
    }
    const int nt = n >> 7, nl = n & 127, kt = kc >> 2, cidx = kc & 3;
    const size_t tbase = (size_t)mat * 262144 + ((size_t)nt * 16 + kt) * 4096;
    const int boff = nl * 64 + ((cidx ^ ((nl >> 1) & 3)) << 4);
    *(int4*)((char*)(Wth + tbase) + boff) = hi.q;
    *(int4*)((char*)(Wtl + tbase) + boff) = lo.q;
}

// ---------------------------------------------------------------------------
// bf16x3-split MFMA GEMM (unchanged from R3).
// ---------------------------------------------------------------------------
template <int OUTMODE>
static __device__ __forceinline__ void gemm3_body(
    const ush* __restrict__ Ah_g, const ush* __restrict__ Al_g,
    const ush* __restrict__ Bh_g, const ush* __restrict__ Bl_g,
    const float* __restrict__ bias, void* __restrict__ outp, float scale) {
    __shared__ char lds[32768];                      // Ah|Al|Bh|Bl, 8KB each
    char* const sAh = lds;
    char* const sAl = lds + 8192;
    char* const sBh = lds + 16384;
    char* const sBl = lds + 24576;

    const int tid = threadIdx.x;
    const int lane = tid & 63, w = tid >> 6;
    const int g = lane >> 4, l15 = lane & 15;
    const int wr = w >> 1, wc = w & 1;
    const int mt = blockIdx.x, nt = blockIdx.y;

    const char* gAh = (const char*)Ah_g + (size_t)(mt * 16) * 8192;
    const char* gAl = (const char*)Al_g + (size_t)(mt * 16) * 8192;
    const char* gBh = (const char*)Bh_g + (size_t)(nt * 16) * 8192;
    const char* gBl = (const char*)Bl_g + (size_t)(nt * 16) * 8192;

    f32x4 acc[4][4];
#pragma unroll
    for (int i = 0; i < 4; ++i)
#pragma unroll
        for (int j = 0; j < 4; ++j)
#pragma unroll
            for (int r = 0; r < 4; ++r) acc[i][j][r] = 0.f;

    const int lw = w * 2048;                         // wave's LDS segment
    for (int kt = 0; kt < 16; ++kt) {
        __syncthreads();                             // prev compute done
        const size_t gb = (size_t)kt * 8192 + lw + lane * 16;
        gload16(gAh + gb,        sAh + lw);
        gload16(gAh + gb + 1024, sAh + lw + 1024);
        gload16(gAl + gb,        sAl + lw);
        gload16(gAl + gb + 1024, sAl + lw + 1024);
        gload16(gBh + gb,        sBh + lw);
        gload16(gBh + gb + 1024, sBh + lw + 1024);
        gload16(gBl + gb,        sBl + lw);
        gload16(gBl + gb + 1024, sBl + lw + 1024);
        __syncthreads();                             // vmcnt(0) drained here

        bf16x8 fah[4], fal[4], fbh[4], fbl[4];
#pragma unroll
        for (int rb = 0; rb < 4; ++rb) {
            const int row = wr * 64 + rb * 16 + l15;
            const int off = row * 64 + ((g ^ ((row >> 1) & 3)) << 4);
            fah[rb] = __builtin_bit_cast(bf16x8, *(const int4*)(sAh + off));
            fal[rb] = __builtin_bit_cast(bf16x8, *(const int4*)(sAl + off));
        }
#pragma unroll
        for (int cb = 0; cb < 4; ++cb) {
            const int row = wc * 64 + cb * 16 + l15;
            const int off = row * 64 + ((g ^ ((row >> 1) & 3)) << 4);
            fbh[cb] = __builtin_bit_cast(bf16x8, *(const int4*)(sBh + off));
            fbl[cb] = __builtin_bit_cast(bf16x8, *(const int4*)(sBl + off));
        }
#pragma unroll
        for (int rb = 0; rb < 4; ++rb)
#pragma unroll
            for (int cb = 0; cb < 4; ++cb) {
                acc[rb][cb] = MFMA16(fah[rb], fbh[cb], acc[rb][cb]);
                acc[rb][cb] = MFMA16(fah[rb], fbl[cb], acc[rb][cb]);
                acc[rb][cb] = MFMA16(fal[rb], fbh[cb], acc[rb][cb]);
            }
    }

    const int mbase = mt * 128 + wr * 64;
    const int nbase = nt * 128 + wc * 64;
    float bcol[4];
#pragma unroll
    for (int cb = 0; cb < 4; ++cb) bcol[cb] = bias[nbase + cb * 16 + l15];

#pragma unroll
    for (int rb = 0; rb < 4; ++rb)
#pragma unroll
        for (int cb = 0; cb < 4; ++cb) {
            const int colg = nbase + cb * 16 + l15;
#pragma unroll
            for (int r = 0; r < 4; ++r) {
                const int m = mbase + rb * 16 + g * 4 + r;
                const float vv = acc[rb][cb][r] + bcol[cb];
                if (OUTMODE == 0) {
                    ((float*)outp)[(size_t)m * C_ + colg] = vv;
                } else {
                    const int bb = m >> 11, t = m & (T_ - 1);
                    const int h = colg >> 6, d = colg & 63;
                    ((ush*)outp)[(((size_t)(bb * H_ + h) * T_ + t) * D_) + d] =
                        f2bf(vv * scale);
                }
            }
        }
}

__global__ __launch_bounds__(256) void gemm3_qkv_kernel(
    const ush* __restrict__ Xh, const ush* __restrict__ Xl,
    const ush* __restrict__ Wth, const ush* __restrict__ Wtl,
    const float* __restrict__ bq, const float* __restrict__ bk,
    const float* __restrict__ bv,
    ush* __restrict__ Qb, ush* __restrict__ Kb, ush* __restrict__ Vb) {
    const int z = blockIdx.z;
    const ush* bh = Wth + (size_t)z * 262144;
    const ush* bl = Wtl + (size_t)z * 262144;
    if (z == 0)      gemm3_body<1>(Xh, Xl, bh, bl, bq, Qb, 0.125f);  // Q pre-scaled
    else if (z == 1) gemm3_body<1>(Xh, Xl, bh, bl, bk, Kb, 1.0f);
    else             gemm3_body<1>(Xh, Xl, bh, bl, bv, Vb, 1.0f);
}

__global__ __launch_bounds__(256) void gemm3_out_kernel(
    const ush* __restrict__ Ch, const ush* __restrict__ Cl,
    const ush* __restrict__ Wth, const ush* __restrict__ Wtl,
    const float* __restrict__ bo, float* __restrict__ out) {
    gemm3_body<0>(Ch, Cl, Wth + (size_t)3 * 262144, Wtl + (size_t)3 * 262144,
                  bo, out, 1.0f);
}

// ---------------------------------------------------------------------------
// Gather compacted K / transposed V into pre-swizzled 8KB tiles (unchanged).
// ---------------------------------------------------------------------------
__global__ __launch_bounds__(256) void gather_kernel(
    const ush* __restrict__ Kb, const ush* __restrict__ Vb,
    const int* __restrict__ klist, const int* __restrict__ kcnt,
    ush* __restrict__ Kc, ush* __restrict__ Vct) {
    __shared__ ush Vs[64 * 72];
    const int tid = threadIdx.x;
    const int ti = blockIdx.x, h = blockIdx.y, b = blockIdx.z;
    const int sel = (h < CDR_HEADS_) ? 1 : 0;
    const int NV = kcnt[b * 2 + sel];
    if (ti * 64 >= NV) return;
    const int* __restrict__ list = klist + (size_t)(b * 2 + sel) * T_;
    const size_t bh = (size_t)b * H_ + h;
    const ush* kb_ = Kb + bh * T_ * D_;
    const ush* vb_ = Vb + bh * T_ * D_;
    ush* kt = Kc + bh * (32 * 4096) + (size_t)ti * 4096;
    ush* vt = Vct + bh * (32 * 4096) + (size_t)ti * 4096;

    const int i = tid >> 2, c = tid & 3;
    const int pos = ti * 64 + i;
    int4 kv0 = {0,0,0,0}, kv1 = {0,0,0,0}, vv0 = {0,0,0,0}, vv1 = {0,0,0,0};
    if (pos < NV) {
        const int row = list[pos];
        const int4* kr = (const int4*)(kb_ + (size_t)row * D_ + c * 16);
        kv0 = kr[0]; kv1 = kr[1];
        const int4* vr = (const int4*)(vb_ + (size_t)row * D_ + c * 16);
        vv0 = vr[0]; vv1 = vr[1];
    }
    {
        const int s0 = (c * 2) ^ (i & 7), s1 = (c * 2 + 1) ^ (i & 7);
        *(int4*)(kt + i * 64 + s0 * 8) = kv0;
        *(int4*)(kt + i * 64 + s1 * 8) = kv1;
    }
    *(int4*)(Vs + i * 72 + c * 16)     = vv0;
    *(int4*)(Vs + i * 72 + c * 16 + 8) = vv1;
    __syncthreads();
    {
        const int d = tid >> 2, c2 = tid & 3;
        union { ush u[16]; int4 q[2]; } pk;
#pragma unroll
        for (int ii = 0; ii < 16; ++ii)
            pk.u[ii] = Vs[(c2 * 16 + ii) * 72 + d];
        const int s0 = (c2 * 2) ^ (d & 7), s1 = (c2 * 2 + 1) ^ (d & 7);
        *(int4*)(vt + d * 64 + s0 * 8) = pk.q[0];
        *(int4*)(vt + d * 64 + s1 * 8) = pk.q[1];
    }
}

// ---------------------------------------------------------------------------
// Kernel 3 v2: bf16 MFMA flash attention.
//  - swapped QK^T (A=K, B=Q) -> C[key][q]: softmax row-reduce is in-lane
//  - single-barrier double-buffered K/V staging via global_load_lds
//  - packed b32 P writes; setprio around MFMA clusters
// ---------------------------------------------------------------------------
__global__ __launch_bounds__(256) void attn_mfma_kernel(
    const ush* __restrict__ Qb, const ush* __restrict__ Kc,
    const ush* __restrict__ Vct, const int* __restrict__ kcnt,
    float* __restrict__ ctx) {
    __shared__ ush Ks[2][4096];
    __shared__ ush Vts[2][4096];
    __shared__ ush Pl[4 * 32 * 72];                  // per-wave P, stride 144B

    const int tid = threadIdx.x;
    const int lane = tid & 63, w = tid >> 6;
    const int g = lane >> 4, l15 = lane & 15;
    const int qt = blockIdx.x, h = blockIdx.y, b = blockIdx.z;
    const int sel = (h < CDR_HEADS_) ? 1 : 0;
    const int NV = kcnt[b * 2 + sel];
    const int ntiles = (NV + 63) >> 6;
    const size_t bh = (size_t)b * H_ + h;
    const int swz = (l15 & 7) << 4;

    // Q fragments: aq[qb][kc]: row = qb*16+l15, d = kc*32 + g*8..+7
    bf16x8 aq[2][2];
    {
        const ush* qp = Qb + (bh * T_ + (size_t)qt * 128 + w * 32) * D_;
#pragma unroll
        for (int qb = 0; qb < 2; ++qb)
#pragma unroll
            for (int kc = 0; kc < 2; ++kc) {
                int4 t4 = *(const int4*)(qp + (qb * 16 + l15) * D_ + kc * 32 + g * 8);
                aq[qb][kc] = __builtin_bit_cast(bf16x8, t4);
            }
    }

    f32x4 cacc[2][4];
#pragma unroll
    for (int qb = 0; qb < 2; ++qb)
#pragma unroll
        for (int db = 0; db < 4; ++db)
#pragma unroll
            for (int r = 0; r < 4; ++r) cacc[qb][db][r] = 0.f;
    float mr[2] = {-INFINITY, -INFINITY};            // per-lane q-row = l15 (per qb)
    float lr[2] = {0.f, 0.f};

    const char* ktiles = (const char*)(Kc + bh * (32 * 4096));
    const char* vtiles = (const char*)(Vct + bh * (32 * 4096));
    ush* Pw = Pl + w * (32 * 72);
    const int lw = w * 1024;                         // wave's 2KB segment (in ush)

    // prologue: stage tile 0 into buffer 0
    gload16(ktiles + lw * 2 + lane * 16, &Ks[0][lw]);
    gload16(ktiles + lw * 2 + 1024 + lane * 16, &Ks[0][lw + 512]);
    gload16(vtiles + lw * 2 + lane * 16, &Vts[0][lw]);
    gload16(vtiles + lw * 2 + 1024 + lane * 16, &Vts[0][lw + 512]);
    __syncthreads();

    for (int t = 0; t < ntiles; ++t) {
        const int cur = t & 1, nxt = cur ^ 1;
        // prefetch next tile (overlaps compute below; drained at the barrier)
        if (t + 1 < ntiles) {
            const char* gk = ktiles + (size_t)(t + 1) * 8192 + lw * 2 + lane * 16;
            const char* gv = vtiles + (size_t)(t + 1) * 8192 + lw * 2 + lane * 16;
            gload16(gk, &Ks[nxt][lw]);
            gload16(gk + 1024, &Ks[nxt][lw + 512]);
            gload16(gv, &Vts[nxt][lw]);
            gload16(gv + 1024, &Vts[nxt][lw + 512]);
        }

        // ---- swapped QK^T: s[qb][j] = C[key_local][q], key = j*16+g*4+r ----
        bf16x8 bk[4][2];
#pragma unroll
        for (int j = 0; j < 4; ++j) {
            const int rowb = (j * 16 + l15) * 128;
            bk[j][0] = __builtin_bit_cast(bf16x8,
                *(const int4*)((const char*)Ks[cur] + ((rowb + g * 16) ^ swz)));
            bk[j][1] = __builtin_bit_cast(bf16x8,
                *(const int4*)((const char*)Ks[cur] + ((rowb + 64 + g * 16) ^ swz)));
        }
        f32x4 s[2][4];
        const f32x4 z4 = {0.f, 0.f, 0.f, 0.f};
        __builtin_amdgcn_s_setprio(1);
#pragma unroll
        for (int j = 0; j < 4; ++j) s[0][j] = MFMA16(bk[j][0], aq[0][0], z4);
#pragma unroll
        for (int j = 0; j < 4; ++j) s[1][j] = MFMA16(bk[j][0], aq[1][0], z4);
#pragma unroll
        for (int j = 0; j < 4; ++j) s[0][j] = MFMA16(bk[j][1], aq[0][1], s[0][j]);
#pragma unroll
        for (int j = 0; j < 4; ++j) s[1][j] = MFMA16(bk[j][1], aq[1][1], s[1][j]);
        __builtin_amdgcn_s_setprio(0);

        // ---- tail mask: key = kb0 + j*16 + g*4 + r >= NV ----
        const int kb0 = t * 64;
        if (kb0 + 64 > NV) {
#pragma unroll
            for (int j = 0; j < 4; ++j)
#pragma unroll
                for (int r = 0; r < 4; ++r)
                    if (kb0 + j * 16 + g * 4 + r >= NV) {
                        s[0][j][r] = -INFINITY;
                        s[1][j][r] = -INFINITY;
                    }
        }

        // ---- online softmax: all 16 values per qb are for q-row = l15 ----
        float rq[2];
#pragma unroll
        for (int qb = 0; qb < 2; ++qb) {
            float mx = s[qb][0][0];
#pragma unroll
            for (int j = 0; j < 4; ++j)
#pragma unroll
                for (int r = 0; r < 4; ++r) mx = fmaxf(mx, s[qb][j][r]);
            mx = fmaxf(mx, __shfl_xor(mx, 16));
            mx = fmaxf(mx, __shfl_xor(mx, 32));
            const float mn = fmaxf(mr[qb], mx);
            rq[qb] = __expf(mr[qb] - mn);            // 0 on first tile
            mr[qb] = mn;
            float sum = 0.f;
#pragma unroll
            for (int j = 0; j < 4; ++j)
#pragma unroll
                for (int r = 0; r < 4; ++r) {
                    const float p = __expf(s[qb][j][r] - mn);
                    s[qb][j][r] = p;
                    sum += p;
                }
            sum += __shfl_xor(sum, 16);
            sum += __shfl_xor(sum, 32);
            lr[qb] = lr[qb] * rq[qb] + sum;
        }

        // ---- rescale cacc: factor for q-row g*4+r fetched from lane g*4+r ----
#pragma unroll
        for (int qb = 0; qb < 2; ++qb)
#pragma unroll
            for (int r = 0; r < 4; ++r) {
                const float rr = __shfl(rq[qb], g * 4 + r, 16);
#pragma unroll
                for (int db = 0; db < 4; ++db) cacc[qb][db][r] *= rr;
            }

        // ---- P -> LDS: row = qb*16 + l15 (q), cols j*16+g*4+{r,r+1} packed ----
#pragma unroll
        for (int qb = 0; qb < 2; ++qb) {
            unsigned* prow = (unsigned*)(Pw + (qb * 16 + l15) * 72);
#pragma unroll
            for (int j = 0; j < 4; ++j) {
                const unsigned p01 = (unsigned)f2bf(s[qb][j][0]) |
                                     ((unsigned)f2bf(s[qb][j][1]) << 16);
                const unsigned p23 = (unsigned)f2bf(s[qb][j][2]) |
                                     ((unsigned)f2bf(s[qb][j][3]) << 16);
                prow[(j * 16 + g * 4) >> 1] = p01;
                prow[(j * 16 + g * 4 + 2) >> 1] = p23;
            }
        }

        // ---- PV: ctx[q][d] += P[q][k] V[k][d] ----
        __builtin_amdgcn_s_setprio(1);
#pragma unroll
        for (int kc = 0; kc < 2; ++kc) {
            bf16x8 pa0 = __builtin_bit_cast(bf16x8,
                *(const int4*)(Pw + l15 * 72 + kc * 32 + g * 8));
            bf16x8 pa1 = __builtin_bit_cast(bf16x8,
                *(const int4*)(Pw + (16 + l15) * 72 + kc * 32 + g * 8));
#pragma unroll
            for (int db = 0; db < 4; ++db) {
                bf16x8 vbf = __builtin_bit_cast(bf16x8,
                    *(const int4*)((const char*)Vts[cur] +
                        ((((db * 16 + l15) * 128) + kc * 64 + g * 16) ^ swz)));
                cacc[0][db] = MFMA16(pa0, vbf, cacc[0][db]);
                cacc[1][db] = MFMA16(pa1, vbf, cacc[1][db]);
            }
        }
        __builtin_amdgcn_s_setprio(0);

        __syncthreads();   // drains prefetch (vmcnt) + protects buffer swap
    }

    // ---- epilogue: normalize + write fp32 ctx [B,T,C] ----
    const size_t trow = (size_t)b * T_ + (size_t)qt * 128 + w * 32;
#pragma unroll
    for (int qb = 0; qb < 2; ++qb)
#pragma unroll
        for (int r = 0; r < 4; ++r) {
            const float lrq = __shfl(lr[qb], g * 4 + r, 16);
            const float inv = 1.f / lrq;
            float* orow = ctx + (trow + qb * 16 + g * 4 + r) * C_ + h * D_;
#pragma unroll
            for (int db = 0; db < 4; ++db)
                orow[db * 16 + l15] = cacc[qb][db][r] * inv;
        }
}

// ---------------------------------------------------------------------------
extern "C" void kernel_launch(void* const* d_in, const int* in_sizes, int n_in,
                              void* d_out, int out_size, void* d_ws, size_t ws_size,
                              hipStream_t stream) {
    const float* x    = (const float*)d_in[0];
    const int*   mask = (const int*)d_in[1];
    const int*   cdrs = (const int*)d_in[2];
    const float* Wq   = (const float*)d_in[3];
    const float* bq   = (const float*)d_in[4];
    const float* Wk   = (const float*)d_in[5];
    const float* bk   = (const float*)d_in[6];
    const float* Wv   = (const float*)d_in[7];
    const float* bv   = (const float*)d_in[8];
    const float* Wo   = (const float*)d_in[9];
    const float* bo   = (const float*)d_in[10];
    float* out = (float*)d_out;

    const size_t per = (size_t)B_ * H_ * T_ * D_;    // 4M elements
    ush* Qb  = (ush*)d_ws;                           // bf16 [B,H,T,D]
    ush* Kb  = Qb + per;
    ush* Vb  = Kb + per;
    ush* Kc  = Vb + per;                             // swizzled K tiles
    ush* Vct = Kc + per;                             // swizzled V^T tiles
    ush* Xh  = Vct + per;                            // x / ctx hi tiles
    ush* Xl  = Xh + per;                             // x / ctx lo tiles
    ush* Wth = Xl + per;                             // 4 matrices W^T hi
    ush* Wtl = Wth + 4 * 262144;                     // 4 matrices W^T lo
    int* klist = (int*)(Wtl + 4 * 262144);
    int* kcnt  = klist + (size_t)B_ * 2 * T_;
    float* ctxf = (float*)Kb;                        // aliases Kb+Vb (dead after gather)

    compact_kernel<<<B_, 256, 0, stream>>>(mask, cdrs, klist, kcnt);

    decomp_a_kernel<<<2048, 256, 0, stream>>>(x, Xh, Xl);
    decomp_w_kernel<<<dim3(128, 4), 256, 0, stream>>>(Wq, Wk, Wv, Wo, Wth, Wtl);

    gemm3_qkv_kernel<<<dim3(64, 4, 3), 256, 0, stream>>>(
        Xh, Xl, Wth, Wtl, bq, bk, bv, Qb, Kb, Vb);

    gather_kernel<<<dim3(32, H_, B_), 256, 0, stream>>>(Kb, Vb, klist, kcnt,
                                                        Kc, Vct);

    attn_mfma_kernel<<<dim3(T_ / 128, H_, B_), 256, 0, stream>>>(
        Qb, Kc, Vct, kcnt, ctxf);

    decomp_a_kernel<<<2048, 256, 0, stream>>>(ctxf, Xh, Xl);

    gemm3_out_kernel<<<dim3(64, 4), 256, 0, stream>>>(Xh, Xl, Wth, Wtl, bo, out);
}

// Round 6
// 198.549 us; speedup vs baseline: 5.7257x; 1.1226x over previous
//
#include <hip/hip_runtime.h>
#include <math.h>

#define B_ 4
#define T_ 2048
#define C_ 512
#define H_ 8
#define D_ 64
#define CDR_HEADS_ 2
#define NROWS (B_ * T_)          // 8192

typedef unsigned short ush;
typedef __bf16  bf16x8 __attribute__((ext_vector_type(8)));
typedef float   f32x4  __attribute__((ext_vector_type(4)));

#define MFMA16(a, b, c) __builtin_amdgcn_mfma_f32_16x16x32_bf16((a), (b), (c), 0, 0, 0)

static __device__ __forceinline__ ush f2bf(float f) {
    unsigned u = __float_as_uint(f);
    u += 0x7FFF + ((u >> 16) & 1);          // RNE
    return (ush)(u >> 16);
}
static __device__ __forceinline__ float bf2f(ush h) {
    return __uint_as_float(((unsigned)h) << 16);
}

// async 16B global->LDS (wave-uniform LDS base + lane*16, per-lane global src)
static __device__ __forceinline__ void gload16(const void* gsrc, void* ldst) {
    __builtin_amdgcn_global_load_lds(
        (const __attribute__((address_space(1))) unsigned int*)gsrc,
        (__attribute__((address_space(3))) unsigned int*)ldst, 16, 0, 0);
}

// ---------------------------------------------------------------------------
// Fused prep kernel: blocks [0,2048) decompose x; [2048,2560) transpose+
// decompose the 4 W matrices; [2560,2564) per-sample key-list compaction.
// ---------------------------------------------------------------------------
__global__ __launch_bounds__(256) void prep_kernel(
    const float* __restrict__ x,
    const float* __restrict__ W0, const float* __restrict__ W1,
    const float* __restrict__ W2, const float* __restrict__ W3,
    const int* __restrict__ mask, const int* __restrict__ cdrs,
    ush* __restrict__ Xh, ush* __restrict__ Xl,
    ush* __restrict__ Wth, ush* __restrict__ Wtl,
    int* __restrict__ klist, int* __restrict__ kcnt) {
    __shared__ int s_any;
    __shared__ int sa[256], sb[256];
    const int bid = blockIdx.x, tid = threadIdx.x;

    if (bid < 2048) {
        // ---- decompose x [8192][512] -> hi/lo tiled-swizzled ----
        const int id = bid * 256 + tid;
        const int m = id >> 6, kc = id & 63;
        const float* p = x + (size_t)m * C_ + kc * 8;
        const float4 a = ((const float4*)p)[0];
        const float4 b2 = ((const float4*)p)[1];
        float xv[8] = {a.x, a.y, a.z, a.w, b2.x, b2.y, b2.z, b2.w};
        union { ush u[8]; int4 q; } hi, lo;
#pragma unroll
        for (int i = 0; i < 8; ++i) {
            const ush h = f2bf(xv[i]);
            hi.u[i] = h;
            lo.u[i] = f2bf(xv[i] - bf2f(h));
        }
        const int mt = m >> 7, ml = m & 127, kt = kc >> 2, cidx = kc & 3;
        const size_t tbase = ((size_t)mt * 16 + kt) * 4096;
        const int boff = ml * 64 + ((cidx ^ ((ml >> 1) & 3)) << 4);
        *(int4*)((char*)(Xh + tbase) + boff) = hi.q;
        *(int4*)((char*)(Xl + tbase) + boff) = lo.q;
    } else if (bid < 2560) {
        // ---- transpose + decompose W -> W^T hi/lo tiled-swizzled ----
        const int z = bid - 2048;
        const int mat = z >> 7;
        const float* W = (mat == 0) ? W0 : (mat == 1) ? W1 : (mat == 2) ? W2 : W3;
        const int id = (z & 127) * 256 + tid;
        const int n = id & 511, kc = id >> 9;
        float xv[8];
#pragma unroll
        for (int j = 0; j < 8; ++j)
            xv[j] = W[(size_t)(kc * 8 + j) * C_ + n];
        union { ush u[8]; int4 q; } hi, lo;
#pragma unroll
        for (int i = 0; i < 8; ++i) {
            const ush h = f2bf(xv[i]);
            hi.u[i] = h;
            lo.u[i] = f2bf(xv[i] - bf2f(h));
        }
        const int nt = n >> 7, nl = n & 127, kt = kc >> 2, cidx = kc & 3;
        const size_t tbase = (size_t)mat * 262144 + ((size_t)nt * 16 + kt) * 4096;
        const int boff = nl * 64 + ((cidx ^ ((nl >> 1) & 3)) << 4);
        *(int4*)((char*)(Wth + tbase) + boff) = hi.q;
        *(int4*)((char*)(Wtl + tbase) + boff) = lo.q;
    } else {
        // ---- key-list compaction for sample b ----
        const int b = bid - 2560;
        if (tid == 0) s_any = 0;
        __syncthreads();
        int m8[8], c8[8];
        int any = 0, ca = 0;
        const int base = b * T_ + tid * 8;
#pragma unroll
        for (int i = 0; i < 8; ++i) {
            m8[i] = mask[base + i];
            c8[i] = cdrs[base + i];
            any |= c8[i];
            ca += (m8[i] != 0);
        }
        if (any) s_any = 1;
        __syncthreads();
        const int en = s_any;
        int cb = 0;
#pragma unroll
        for (int i = 0; i < 8; ++i)
            cb += (m8[i] != 0 && (!en || c8[i] != 0));
        sa[tid] = ca; sb[tid] = cb;
        __syncthreads();
        for (int off = 1; off < 256; off <<= 1) {
            int va = 0, vb = 0;
            if (tid >= off) { va = sa[tid - off]; vb = sb[tid - off]; }
            __syncthreads();
            sa[tid] += va; sb[tid] += vb;
            __syncthreads();
        }
        int offA = sa[tid] - ca;
        int offB = sb[tid] - cb;
        int* la = klist + (size_t)(b * 2 + 0) * T_;
        int* lb = klist + (size_t)(b * 2 + 1) * T_;
#pragma unroll
        for (int i = 0; i < 8; ++i) {
            const int t = tid * 8 + i;
            if (m8[i] != 0) la[offA++] = t;
            if (m8[i] != 0 && (!en || c8[i] != 0)) lb[offB++] = t;
        }
        if (tid == 255) {
            kcnt[b * 2 + 0] = sa[255];
            kcnt[b * 2 + 1] = sb[255];
        }
    }
}

// ---------------------------------------------------------------------------
// bf16x3-split MFMA GEMM (unchanged).
// ---------------------------------------------------------------------------
template <int OUTMODE>
static __device__ __forceinline__ void gemm3_body(
    const ush* __restrict__ Ah_g, const ush* __restrict__ Al_g,
    const ush* __restrict__ Bh_g, const ush* __restrict__ Bl_g,
    const float* __restrict__ bias, void* __restrict__ outp, float scale) {
    __shared__ char lds[32768];                      // Ah|Al|Bh|Bl, 8KB each
    char* const sAh = lds;
    char* const sAl = lds + 8192;
    char* const sBh = lds + 16384;
    char* const sBl = lds + 24576;

    const int tid = threadIdx.x;
    const int lane = tid & 63, w = tid >> 6;
    const int g = lane >> 4, l15 = lane & 15;
    const int wr = w >> 1, wc = w & 1;
    const int mt = blockIdx.x, nt = blockIdx.y;

    const char* gAh = (const char*)Ah_g + (size_t)(mt * 16) * 8192;
    const char* gAl = (const char*)Al_g + (size_t)(mt * 16) * 8192;
    const char* gBh = (const char*)Bh_g + (size_t)(nt * 16) * 8192;
    const char* gBl = (const char*)Bl_g + (size_t)(nt * 16) * 8192;

    f32x4 acc[4][4];
#pragma unroll
    for (int i = 0; i < 4; ++i)
#pragma unroll
        for (int j = 0; j < 4; ++j)
#pragma unroll
            for (int r = 0; r < 4; ++r) acc[i][j][r] = 0.f;

    const int lw = w * 2048;                         // wave's LDS segment
    for (int kt = 0; kt < 16; ++kt) {
        __syncthreads();
        const size_t gb = (size_t)kt * 8192 + lw + lane * 16;
        gload16(gAh + gb,        sAh + lw);
        gload16(gAh + gb + 1024, sAh + lw + 1024);
        gload16(gAl + gb,        sAl + lw);
        gload16(gAl + gb + 1024, sAl + lw + 1024);
        gload16(gBh + gb,        sBh + lw);
        gload16(gBh + gb + 1024, sBh + lw + 1024);
        gload16(gBl + gb,        sBl + lw);
        gload16(gBl + gb + 1024, sBl + lw + 1024);
        __syncthreads();

        bf16x8 fah[4], fal[4], fbh[4], fbl[4];
#pragma unroll
        for (int rb = 0; rb < 4; ++rb) {
            const int row = wr * 64 + rb * 16 + l15;
            const int off = row * 64 + ((g ^ ((row >> 1) & 3)) << 4);
            fah[rb] = __builtin_bit_cast(bf16x8, *(const int4*)(sAh + off));
            fal[rb] = __builtin_bit_cast(bf16x8, *(const int4*)(sAl + off));
        }
#pragma unroll
        for (int cb = 0; cb < 4; ++cb) {
            const int row = wc * 64 + cb * 16 + l15;
            const int off = row * 64 + ((g ^ ((row >> 1) & 3)) << 4);
            fbh[cb] = __builtin_bit_cast(bf16x8, *(const int4*)(sBh + off));
            fbl[cb] = __builtin_bit_cast(bf16x8, *(const int4*)(sBl + off));
        }
#pragma unroll
        for (int rb = 0; rb < 4; ++rb)
#pragma unroll
            for (int cb = 0; cb < 4; ++cb) {
                acc[rb][cb] = MFMA16(fah[rb], fbh[cb], acc[rb][cb]);
                acc[rb][cb] = MFMA16(fah[rb], fbl[cb], acc[rb][cb]);
                acc[rb][cb] = MFMA16(fal[rb], fbh[cb], acc[rb][cb]);
            }
    }

    const int mbase = mt * 128 + wr * 64;
    const int nbase = nt * 128 + wc * 64;
    float bcol[4];
#pragma unroll
    for (int cb = 0; cb < 4; ++cb) bcol[cb] = bias[nbase + cb * 16 + l15];

#pragma unroll
    for (int rb = 0; rb < 4; ++rb)
#pragma unroll
        for (int cb = 0; cb < 4; ++cb) {
            const int colg = nbase + cb * 16 + l15;
#pragma unroll
            for (int r = 0; r < 4; ++r) {
                const int m = mbase + rb * 16 + g * 4 + r;
                const float vv = acc[rb][cb][r] + bcol[cb];
                if (OUTMODE == 0) {
                    ((float*)outp)[(size_t)m * C_ + colg] = vv;
                } else {
                    const int bb = m >> 11, t = m & (T_ - 1);
                    const int h = colg >> 6, d = colg & 63;
                    ((ush*)outp)[(((size_t)(bb * H_ + h) * T_ + t) * D_) + d] =
                        f2bf(vv * scale);
                }
            }
        }
}

__global__ __launch_bounds__(256) void gemm3_qkv_kernel(
    const ush* __restrict__ Xh, const ush* __restrict__ Xl,
    const ush* __restrict__ Wth, const ush* __restrict__ Wtl,
    const float* __restrict__ bq, const float* __restrict__ bk,
    const float* __restrict__ bv,
    ush* __restrict__ Qb, ush* __restrict__ Kb, ush* __restrict__ Vb) {
    const int z = blockIdx.z;
    const ush* bh = Wth + (size_t)z * 262144;
    const ush* bl = Wtl + (size_t)z * 262144;
    if (z == 0)      gemm3_body<1>(Xh, Xl, bh, bl, bq, Qb, 0.125f);  // Q pre-scaled
    else if (z == 1) gemm3_body<1>(Xh, Xl, bh, bl, bk, Kb, 1.0f);
    else             gemm3_body<1>(Xh, Xl, bh, bl, bv, Vb, 1.0f);
}

__global__ __launch_bounds__(256) void gemm3_out_kernel(
    const ush* __restrict__ Ch, const ush* __restrict__ Cl,
    const ush* __restrict__ Wth, const ush* __restrict__ Wtl,
    const float* __restrict__ bo, float* __restrict__ out) {
    gemm3_body<0>(Ch, Cl, Wth + (size_t)3 * 262144, Wtl + (size_t)3 * 262144,
                  bo, out, 1.0f);
}

// ---------------------------------------------------------------------------
// Gather compacted K / transposed V into pre-swizzled 8KB tiles (unchanged).
// ---------------------------------------------------------------------------
__global__ __launch_bounds__(256) void gather_kernel(
    const ush* __restrict__ Kb, const ush* __restrict__ Vb,
    const int* __restrict__ klist, const int* __restrict__ kcnt,
    ush* __restrict__ Kc, ush* __restrict__ Vct) {
    __shared__ ush Vs[64 * 72];
    const int tid = threadIdx.x;
    const int ti = blockIdx.x, h = blockIdx.y, b = blockIdx.z;
    const int sel = (h < CDR_HEADS_) ? 1 : 0;
    const int NV = kcnt[b * 2 + sel];
    if (ti * 64 >= NV) return;
    const int* __restrict__ list = klist + (size_t)(b * 2 + sel) * T_;
    const size_t bh = (size_t)b * H_ + h;
    const ush* kb_ = Kb + bh * T_ * D_;
    const ush* vb_ = Vb + bh * T_ * D_;
    ush* kt = Kc + bh * (32 * 4096) + (size_t)ti * 4096;
    ush* vt = Vct + bh * (32 * 4096) + (size_t)ti * 4096;

    const int i = tid >> 2, c = tid & 3;
    const int pos = ti * 64 + i;
    int4 kv0 = {0,0,0,0}, kv1 = {0,0,0,0}, vv0 = {0,0,0,0}, vv1 = {0,0,0,0};
    if (pos < NV) {
        const int row = list[pos];
        const int4* kr = (const int4*)(kb_ + (size_t)row * D_ + c * 16);
        kv0 = kr[0]; kv1 = kr[1];
        const int4* vr = (const int4*)(vb_ + (size_t)row * D_ + c * 16);
        vv0 = vr[0]; vv1 = vr[1];
    }
    {
        const int s0 = (c * 2) ^ (i & 7), s1 = (c * 2 + 1) ^ (i & 7);
        *(int4*)(kt + i * 64 + s0 * 8) = kv0;
        *(int4*)(kt + i * 64 + s1 * 8) = kv1;
    }
    *(int4*)(Vs + i * 72 + c * 16)     = vv0;
    *(int4*)(Vs + i * 72 + c * 16 + 8) = vv1;
    __syncthreads();
    {
        const int d = tid >> 2, c2 = tid & 3;
        union { ush u[16]; int4 q[2]; } pk;
#pragma unroll
        for (int ii = 0; ii < 16; ++ii)
            pk.u[ii] = Vs[(c2 * 16 + ii) * 72 + d];
        const int s0 = (c2 * 2) ^ (d & 7), s1 = (c2 * 2 + 1) ^ (d & 7);
        *(int4*)(vt + d * 64 + s0 * 8) = pk.q[0];
        *(int4*)(vt + d * 64 + s1 * 8) = pk.q[1];
    }
}

// ---------------------------------------------------------------------------
// Kernel 3 v3: bf16 MFMA flash attention, 8 waves x 16 q-rows.
//  - swapped QK^T; in-lane softmax; defer-max (THR=8)
//  - P in per-wave swizzled LDS tile (same format as K tiles)
//  - dbuf prefetch staging; fused hi/lo decomposed epilogue -> Xh/Xl
// ---------------------------------------------------------------------------
__global__ __launch_bounds__(512) void attn_mfma_kernel(
    const ush* __restrict__ Qb, const ush* __restrict__ Kc,
    const ush* __restrict__ Vct, const int* __restrict__ kcnt,
    ush* __restrict__ Xh, ush* __restrict__ Xl) {
    __shared__ ush Ks[2][4096];
    __shared__ ush Vts[2][4096];
    __shared__ ush Pl[8192];                 // 8 waves x 16 rows x 128B (swizzled)

    const int tid = threadIdx.x;
    const int lane = tid & 63, w = tid >> 6;
    const int g = lane >> 4, l15 = lane & 15;

    // flat grid -> XCD-balanced (b,h,qt): x = (h + 2b) & 7
    const int i = blockIdx.x;
    const int x7 = i & 7, local = i >> 3;
    const int b = local >> 4;                // slot 0..3
    const int h = (x7 - 2 * b) & 7;
    const int qt = local & 15;
    const int bh = b * H_ + h;

    const int sel = (h < CDR_HEADS_) ? 1 : 0;
    const int NV = kcnt[b * 2 + sel];
    const int ntiles = (NV + 63) >> 6;
    const int swz = (l15 & 7) << 4;

    // Q fragments: 16 q rows per wave; row = l15, k = kc*32 + g*8..+7
    bf16x8 aq[2];
    {
        const ush* qp = Qb + ((size_t)bh * T_ + qt * 128 + w * 16) * D_;
#pragma unroll
        for (int kc = 0; kc < 2; ++kc)
            aq[kc] = __builtin_bit_cast(bf16x8,
                *(const int4*)(qp + l15 * D_ + kc * 32 + g * 8));
    }

    f32x4 cacc[4];
#pragma unroll
    for (int db = 0; db < 4; ++db)
#pragma unroll
        for (int r = 0; r < 4; ++r) cacc[db][r] = 0.f;
    float mr = -INFINITY, lr = 0.f;

    const char* ktiles = (const char*)(Kc + (size_t)bh * (32 * 4096));
    const char* vtiles = (const char*)(Vct + (size_t)bh * (32 * 4096));
    char* Pw = (char*)Pl + w * 2048;         // 16 rows x 128B, per-wave private
    const int lwo = w * 512;                 // wave's 1KB slice (ush offset)

    // prologue: stage tile 0
    gload16(ktiles + lwo * 2 + lane * 16, &Ks[0][lwo]);
    gload16(vtiles + lwo * 2 + lane * 16, &Vts[0][lwo]);
    __syncthreads();

    for (int t = 0; t < ntiles; ++t) {
        const int cur = t & 1, nxt = cur ^ 1;
        if (t + 1 < ntiles) {
            gload16(ktiles + (size_t)(t + 1) * 8192 + lwo * 2 + lane * 16,
                    &Ks[nxt][lwo]);
            gload16(vtiles + (size_t)(t + 1) * 8192 + lwo * 2 + lane * 16,
                    &Vts[nxt][lwo]);
        }

        // ---- swapped QK^T: s[j] = C[key][q], key = j*16+g*4+r, q = l15 ----
        bf16x8 bk[4][2];
#pragma unroll
        for (int j = 0; j < 4; ++j) {
            const int rowb = (j * 16 + l15) * 128;
            bk[j][0] = __builtin_bit_cast(bf16x8,
                *(const int4*)((const char*)Ks[cur] + ((rowb + g * 16) ^ swz)));
            bk[j][1] = __builtin_bit_cast(bf16x8,
                *(const int4*)((const char*)Ks[cur] + ((rowb + 64 + g * 16) ^ swz)));
        }
        f32x4 s[4];
        const f32x4 z4 = {0.f, 0.f, 0.f, 0.f};
        __builtin_amdgcn_s_setprio(1);
#pragma unroll
        for (int j = 0; j < 4; ++j) s[j] = MFMA16(bk[j][0], aq[0], z4);
#pragma unroll
        for (int j = 0; j < 4; ++j) s[j] = MFMA16(bk[j][1], aq[1], s[j]);
        __builtin_amdgcn_s_setprio(0);

        // ---- tail mask ----
        const int kb0 = t * 64;
        if (kb0 + 64 > NV) {
#pragma unroll
            for (int j = 0; j < 4; ++j)
#pragma unroll
                for (int r = 0; r < 4; ++r)
                    if (kb0 + j * 16 + g * 4 + r >= NV) s[j][r] = -INFINITY;
        }

        // ---- online softmax with defer-max ----
        float pmax = s[0][0];
#pragma unroll
        for (int j = 0; j < 4; ++j)
#pragma unroll
            for (int r = 0; r < 4; ++r) pmax = fmaxf(pmax, s[j][r]);
        pmax = fmaxf(pmax, __shfl_xor(pmax, 16));
        pmax = fmaxf(pmax, __shfl_xor(pmax, 32));
        if (!__all(pmax <= mr + 8.f)) {
            const float mn = fmaxf(mr, pmax);
            const float rr = __expf(mr - mn);       // 0 on first tile
            mr = mn;
            lr *= rr;
#pragma unroll
            for (int r = 0; r < 4; ++r) {
                const float rrq = __shfl(rr, g * 4 + r, 16);
#pragma unroll
                for (int db = 0; db < 4; ++db) cacc[db][r] *= rrq;
            }
        }
        float sum = 0.f;
#pragma unroll
        for (int j = 0; j < 4; ++j)
#pragma unroll
            for (int r = 0; r < 4; ++r) {
                const float p = __expf(s[j][r] - mr);
                s[j][r] = p;
                sum += p;
            }
        sum += __shfl_xor(sum, 16);
        sum += __shfl_xor(sum, 32);
        lr += sum;

        // ---- P -> swizzled LDS tile: row q=l15, keys j*16+g*4..+3 ----
#pragma unroll
        for (int j = 0; j < 4; ++j) {
            const ush u0 = __builtin_bit_cast(ush, (__bf16)s[j][0]);
            const ush u1 = __builtin_bit_cast(ush, (__bf16)s[j][1]);
            const ush u2 = __builtin_bit_cast(ush, (__bf16)s[j][2]);
            const ush u3 = __builtin_bit_cast(ush, (__bf16)s[j][3]);
            uint2 pk;
            pk.x = (unsigned)u0 | ((unsigned)u1 << 16);
            pk.y = (unsigned)u2 | ((unsigned)u3 << 16);
            const int sb = (j * 2 + (g >> 1)) ^ (l15 & 7);
            *(uint2*)(Pw + l15 * 128 + sb * 16 + (g & 1) * 8) = pk;
        }

        // ---- PV: pa row q=l15, k = kc*32+g*8..+7 ----
        bf16x8 pa[2];
#pragma unroll
        for (int kc = 0; kc < 2; ++kc)
            pa[kc] = __builtin_bit_cast(bf16x8,
                *(const int4*)(Pw + l15 * 128 + (((kc * 4 + g) ^ (l15 & 7)) << 4)));
        __builtin_amdgcn_s_setprio(1);
#pragma unroll
        for (int kc = 0; kc < 2; ++kc)
#pragma unroll
            for (int db = 0; db < 4; ++db) {
                bf16x8 vbf = __builtin_bit_cast(bf16x8,
                    *(const int4*)((const char*)Vts[cur] +
                        ((((db * 16 + l15) * 128) + kc * 64 + g * 16) ^ swz)));
                cacc[db] = MFMA16(pa[kc], vbf, cacc[db]);
            }
        __builtin_amdgcn_s_setprio(0);

        __syncthreads();   // drains prefetch + protects buffer swap
    }

    // ---- fused epilogue: normalize + hi/lo decompose -> swizzled Xh/Xl ----
    const int mt = b * 16 + qt;              // 128-row tile index
#pragma unroll
    for (int r = 0; r < 4; ++r) {
        const float lrq = __shfl(lr, g * 4 + r, 16);
        const float inv = 1.f / lrq;
        const int ml = w * 16 + g * 4 + r;
#pragma unroll
        for (int db = 0; db < 4; ++db) {
            const int col = h * 64 + db * 16 + l15;
            const float val = cacc[db][r] * inv;
            const __bf16 hb = (__bf16)val;
            const __bf16 lb2 = (__bf16)(val - (float)hb);
            const int kt2 = col >> 5;
            const int cidx = (col >> 3) & 3;
            const size_t tb = ((size_t)mt * 16 + kt2) * 4096;
            const int boff = ml * 64 + ((cidx ^ ((ml >> 1) & 3)) << 4) + (l15 & 7) * 2;
            *(ush*)((char*)(Xh + tb) + boff) = __builtin_bit_cast(ush, hb);
            *(ush*)((char*)(Xl + tb) + boff) = __builtin_bit_cast(ush, lb2);
        }
    }
}

// ---------------------------------------------------------------------------
extern "C" void kernel_launch(void* const* d_in, const int* in_sizes, int n_in,
                              void* d_out, int out_size, void* d_ws, size_t ws_size,
                              hipStream_t stream) {
    const float* x    = (const float*)d_in[0];
    const int*   mask = (const int*)d_in[1];
    const int*   cdrs = (const int*)d_in[2];
    const float* Wq   = (const float*)d_in[3];
    const float* bq   = (const float*)d_in[4];
    const float* Wk   = (const float*)d_in[5];
    const float* bk   = (const float*)d_in[6];
    const float* Wv   = (const float*)d_in[7];
    const float* bv   = (const float*)d_in[8];
    const float* Wo   = (const float*)d_in[9];
    const float* bo   = (const float*)d_in[10];
    float* out = (float*)d_out;

    const size_t per = (size_t)B_ * H_ * T_ * D_;    // 4M elements
    ush* Qb  = (ush*)d_ws;                           // bf16 [B,H,T,D]
    ush* Kb  = Qb + per;
    ush* Vb  = Kb + per;
    ush* Kc  = Vb + per;                             // swizzled K tiles
    ush* Vct = Kc + per;                             // swizzled V^T tiles
    ush* Xh  = Vct + per;                            // x / ctx hi tiles
    ush* Xl  = Xh + per;                             // x / ctx lo tiles
    ush* Wth = Xl + per;                             // 4 matrices W^T hi
    ush* Wtl = Wth + 4 * 262144;                     // 4 matrices W^T lo
    int* klist = (int*)(Wtl + 4 * 262144);
    int* kcnt  = klist + (size_t)B_ * 2 * T_;

    prep_kernel<<<2564, 256, 0, stream>>>(x, Wq, Wk, Wv, Wo, mask, cdrs,
                                          Xh, Xl, Wth, Wtl, klist, kcnt);

    gemm3_qkv_kernel<<<dim3(64, 4, 3), 256, 0, stream>>>(
        Xh, Xl, Wth, Wtl, bq, bk, bv, Qb, Kb, Vb);

    gather_kernel<<<dim3(32, H_, B_), 256, 0, stream>>>(Kb, Vb, klist, kcnt,
                                                        Kc, Vct);

    attn_mfma_kernel<<<512, 512, 0, stream>>>(Qb, Kc, Vct, kcnt, Xh, Xl);

    gemm3_out_kernel<<<dim3(64, 4), 256, 0, stream>>>(Xh, Xl, Wth, Wtl, bo, out);
}

// Round 10
// 191.007 us; speedup vs baseline: 5.9518x; 1.0395x over previous
//
#include <hip/hip_runtime.h>
#include <math.h>

#define B_ 4
#define T_ 2048
#define C_ 512
#define H_ 8
#define D_ 64
#define CDR_HEADS_ 2
#define NROWS (B_ * T_)          // 8192

typedef unsigned short ush;
typedef __bf16  bf16x8 __attribute__((ext_vector_type(8)));
typedef float   f32x4  __attribute__((ext_vector_type(4)));

#define MFMA16(a, b, c) __builtin_amdgcn_mfma_f32_16x16x32_bf16((a), (b), (c), 0, 0, 0)

static __device__ __forceinline__ ush f2bf(float f) {
    unsigned u = __float_as_uint(f);
    u += 0x7FFF + ((u >> 16) & 1);          // RNE
    return (ush)(u >> 16);
}
static __device__ __forceinline__ float bf2f(ush h) {
    return __uint_as_float(((unsigned)h) << 16);
}

// async 16B global->LDS (wave-uniform LDS base + lane*16, per-lane global src)
static __device__ __forceinline__ void gload16(const void* gsrc, void* ldst) {
    __builtin_amdgcn_global_load_lds(
        (const __attribute__((address_space(1))) unsigned int*)gsrc,
        (__attribute__((address_space(3))) unsigned int*)ldst, 16, 0, 0);
}

// ---------------------------------------------------------------------------
// Fused prep kernel: [0,2048) decompose x; [2048,2560) transpose+decompose W;
// [2560,2564) per-sample compaction -> inverse position maps + counts.
// ---------------------------------------------------------------------------
__global__ __launch_bounds__(256) void prep_kernel(
    const float* __restrict__ x,
    const float* __restrict__ W0, const float* __restrict__ W1,
    const float* __restrict__ W2, const float* __restrict__ W3,
    const int* __restrict__ mask, const int* __restrict__ cdrs,
    ush* __restrict__ Xh, ush* __restrict__ Xl,
    ush* __restrict__ Wth, ush* __restrict__ Wtl,
    int* __restrict__ posA, int* __restrict__ posB, int* __restrict__ kcnt) {
    __shared__ int s_any;
    __shared__ int sa[256], sb[256];
    const int bid = blockIdx.x, tid = threadIdx.x;

    if (bid < 2048) {
        // ---- decompose x [8192][512] -> hi/lo tiled-swizzled ----
        const int id = bid * 256 + tid;
        const int m = id >> 6, kc = id & 63;
        const float* p = x + (size_t)m * C_ + kc * 8;
        const float4 a = ((const float4*)p)[0];
        const float4 b2 = ((const float4*)p)[1];
        float xv[8] = {a.x, a.y, a.z, a.w, b2.x, b2.y, b2.z, b2.w};
        union { ush u[8]; int4 q; } hi, lo;
#pragma unroll
        for (int i = 0; i < 8; ++i) {
            const ush h = f2bf(xv[i]);
            hi.u[i] = h;
            lo.u[i] = f2bf(xv[i] - bf2f(h));
        }
        const int mt = m >> 7, ml = m & 127, kt = kc >> 2, cidx = kc & 3;
        const size_t tbase = ((size_t)mt * 16 + kt) * 4096;
        const int boff = ml * 64 + ((cidx ^ ((ml >> 1) & 3)) << 4);
        *(int4*)((char*)(Xh + tbase) + boff) = hi.q;
        *(int4*)((char*)(Xl + tbase) + boff) = lo.q;
    } else if (bid < 2560) {
        // ---- transpose + decompose W -> W^T hi/lo tiled-swizzled ----
        const int z = bid - 2048;
        const int mat = z >> 7;
        const float* W = (mat == 0) ? W0 : (mat == 1) ? W1 : (mat == 2) ? W2 : W3;
        const int id = (z & 127) * 256 + tid;
        const int n = id & 511, kc = id >> 9;
        float xv[8];
#pragma unroll
        for (int j = 0; j < 8; ++j)
            xv[j] = W[(size_t)(kc * 8 + j) * C_ + n];
        union { ush u[8]; int4 q; } hi, lo;
#pragma unroll
        for (int i = 0; i < 8; ++i) {
            const ush h = f2bf(xv[i]);
            hi.u[i] = h;
            lo.u[i] = f2bf(xv[i] - bf2f(h));
        }
        const int nt = n >> 7, nl = n & 127, kt = kc >> 2, cidx = kc & 3;
        const size_t tbase = (size_t)mat * 262144 + ((size_t)nt * 16 + kt) * 4096;
        const int boff = nl * 64 + ((cidx ^ ((nl >> 1) & 3)) << 4);
        *(int4*)((char*)(Wth + tbase) + boff) = hi.q;
        *(int4*)((char*)(Wtl + tbase) + boff) = lo.q;
    } else {
        // ---- compaction for sample b: inverse maps posA/posB + counts ----
        const int b = bid - 2560;
        if (tid == 0) s_any = 0;
        __syncthreads();
        int m8[8], c8[8];
        int any = 0, ca = 0;
        const int base = b * T_ + tid * 8;
#pragma unroll
        for (int i = 0; i < 8; ++i) {
            m8[i] = mask[base + i];
            c8[i] = cdrs[base + i];
            any |= c8[i];
            ca += (m8[i] != 0);
        }
        if (any) s_any = 1;
        __syncthreads();
        const int en = s_any;
        int cb = 0;
#pragma unroll
        for (int i = 0; i < 8; ++i)
            cb += (m8[i] != 0 && (!en || c8[i] != 0));
        sa[tid] = ca; sb[tid] = cb;
        __syncthreads();
        for (int off = 1; off < 256; off <<= 1) {
            int va = 0, vb = 0;
            if (tid >= off) { va = sa[tid - off]; vb = sb[tid - off]; }
            __syncthreads();
            sa[tid] += va; sb[tid] += vb;
            __syncthreads();
        }
        int offA = sa[tid] - ca;
        int offB = sb[tid] - cb;
#pragma unroll
        for (int i = 0; i < 8; ++i) {
            const int t = tid * 8 + i;
            const bool av = (m8[i] != 0);
            const bool bv = av && (!en || c8[i] != 0);
            posA[b * T_ + t] = av ? offA++ : -1;
            posB[b * T_ + t] = bv ? offB++ : -1;
        }
        if (tid == 255) {
            kcnt[b * 2 + 0] = sa[255];
            kcnt[b * 2 + 1] = sb[255];
        }
    }
}

// ---------------------------------------------------------------------------
// bf16x3-split MFMA GEMM, 2-phase double-buffered staging.
// LDS buffer (2 x 32KB) is passed in from kernel scope (shared by all
// template instantiations in one kernel -- avoids 3x LDS duplication).
// OUTMODE 0: fp32 row-major [M,C_].   OUTMODE 1: Q bf16 heads * scale.
// OUTMODE 2: K scatter -> swizzled Kc tiles.  OUTMODE 3: V scatter -> Vct.
// ---------------------------------------------------------------------------
template <int OUTMODE>
static __device__ __forceinline__ void gemm3_body(
    char* __restrict__ lds0, char* __restrict__ lds1,
    int mt, int nt,
    const ush* __restrict__ Ah_g, const ush* __restrict__ Al_g,
    const ush* __restrict__ Bh_g, const ush* __restrict__ Bl_g,
    const float* __restrict__ bias, void* __restrict__ outp, float scale,
    const int* __restrict__ posA, const int* __restrict__ posB,
    ush* __restrict__ Kc, ush* __restrict__ Vct) {
    const int tid = threadIdx.x;
    const int lane = tid & 63, w = tid >> 6;
    const int g = lane >> 4, l15 = lane & 15;
    const int wr = w >> 1, wc = w & 1;

    const char* gAh = (const char*)Ah_g + (size_t)(mt * 16) * 8192;
    const char* gAl = (const char*)Al_g + (size_t)(mt * 16) * 8192;
    const char* gBh = (const char*)Bh_g + (size_t)(nt * 16) * 8192;
    const char* gBl = (const char*)Bl_g + (size_t)(nt * 16) * 8192;

    const int lw = w * 2048;                         // wave's segment in each 8KB

    f32x4 acc[4][4];
#pragma unroll
    for (int i = 0; i < 4; ++i)
#pragma unroll
        for (int j = 0; j < 4; ++j)
#pragma unroll
            for (int r = 0; r < 4; ++r) acc[i][j][r] = 0.f;

    // stage K-step kt into buffer buf (8 x 1KB gloads per wave)
    auto stage = [&](char* s, int kt) {
        const size_t gb = (size_t)kt * 8192 + lw + lane * 16;
        gload16(gAh + gb,        s + lw);
        gload16(gAh + gb + 1024, s + lw + 1024);
        gload16(gAl + gb,        s + 8192 + lw);
        gload16(gAl + gb + 1024, s + 8192 + lw + 1024);
        gload16(gBh + gb,        s + 16384 + lw);
        gload16(gBh + gb + 1024, s + 16384 + lw + 1024);
        gload16(gBl + gb,        s + 24576 + lw);
        gload16(gBl + gb + 1024, s + 24576 + lw + 1024);
    };

    stage(lds0, 0);
    __syncthreads();                                 // buf0 ready (vmcnt drained)

    for (int kt = 0; kt < 16; ++kt) {
        char* s  = (kt & 1) ? lds1 : lds0;
        char* sn = (kt & 1) ? lds0 : lds1;
        if (kt + 1 < 16) stage(sn, kt + 1);          // in flight during compute

        bf16x8 fah[4], fal[4], fbh[4], fbl[4];
#pragma unroll
        for (int rb = 0; rb < 4; ++rb) {
            const int row = wr * 64 + rb * 16 + l15;
            const int off = row * 64 + ((g ^ ((row >> 1) & 3)) << 4);
            fah[rb] = __builtin_bit_cast(bf16x8, *(const int4*)(s + off));
            fal[rb] = __builtin_bit_cast(bf16x8, *(const int4*)(s + 8192 + off));
        }
#pragma unroll
        for (int cb = 0; cb < 4; ++cb) {
            const int row = wc * 64 + cb * 16 + l15;
            const int off = row * 64 + ((g ^ ((row >> 1) & 3)) << 4);
            fbh[cb] = __builtin_bit_cast(bf16x8, *(const int4*)(s + 16384 + off));
            fbl[cb] = __builtin_bit_cast(bf16x8, *(const int4*)(s + 24576 + off));
        }
        __builtin_amdgcn_s_setprio(1);
#pragma unroll
        for (int rb = 0; rb < 4; ++rb)
#pragma unroll
            for (int cb = 0; cb < 4; ++cb) {
                acc[rb][cb] = MFMA16(fah[rb], fbh[cb], acc[rb][cb]);
                acc[rb][cb] = MFMA16(fah[rb], fbl[cb], acc[rb][cb]);
                acc[rb][cb] = MFMA16(fal[rb], fbh[cb], acc[rb][cb]);
            }
        __builtin_amdgcn_s_setprio(0);
        __syncthreads();   // drains prefetch; protects buffer swap
    }

    // ---- epilogue ----
    const int mbase = mt * 128 + wr * 64;
    const int nbase = nt * 128 + wc * 64;
    float bcol[4];
#pragma unroll
    for (int cb = 0; cb < 4; ++cb) bcol[cb] = bias[nbase + cb * 16 + l15];

#pragma unroll
    for (int rb = 0; rb < 4; ++rb)
#pragma unroll
        for (int cb = 0; cb < 4; ++cb) {
            const int colg = nbase + cb * 16 + l15;
#pragma unroll
            for (int r = 0; r < 4; ++r) {
                const int m = mbase + rb * 16 + g * 4 + r;
                const float vv = acc[rb][cb][r] + bcol[cb];
                if (OUTMODE == 0) {
                    ((float*)outp)[(size_t)m * C_ + colg] = vv;
                } else if (OUTMODE == 1) {
                    const int bb = m >> 11, t = m & (T_ - 1);
                    const int h = colg >> 6, d = colg & 63;
                    ((ush*)outp)[(((size_t)(bb * H_ + h) * T_ + t) * D_) + d] =
                        f2bf(vv * scale);
                } else {
                    const int bb = m >> 11, t = m & (T_ - 1);
                    const int h = colg >> 6, d = colg & 63;
                    const int pos = (h < CDR_HEADS_ ? posB : posA)[bb * T_ + t];
                    if (pos >= 0) {
                        // tile stride is 8192 BYTES (64 keys x 128B)
                        char* base = (char*)(OUTMODE == 2 ? Kc : Vct) +
                                     (size_t)(bb * H_ + h) * 262144 +
                                     (size_t)(pos >> 6) * 8192;
                        const int i = pos & 63;
                        const ush val = f2bf(vv);
                        if (OUTMODE == 2)
                            *(ush*)(base + i * 128 + (((d >> 3) ^ (i & 7)) << 4) +
                                    (d & 7) * 2) = val;
                        else
                            *(ush*)(base + d * 128 + (((i >> 3) ^ (d & 7)) << 4) +
                                    (i & 7) * 2) = val;
                    }
                }
            }
        }
}

// QKV: flat grid 768, chunked XCD swizzle; wg -> (mt, nt, z)
__global__ __launch_bounds__(256) void gemm3_qkv_kernel(
    const ush* __restrict__ Xh, const ush* __restrict__ Xl,
    const ush* __restrict__ Wth, const ush* __restrict__ Wtl,
    const float* __restrict__ bq, const float* __restrict__ bk,
    const float* __restrict__ bv, ush* __restrict__ Qb,
    const int* __restrict__ posA, const int* __restrict__ posB,
    ush* __restrict__ Kc, ush* __restrict__ Vct) {
    __shared__ char lds[2][32768];                   // shared by all arms
    const int wg = (blockIdx.x & 7) * 96 + (blockIdx.x >> 3);   // 768 = 8*96
    const int mt = wg / 12, sub = wg % 12;
    const int nt = sub & 3, z = sub >> 2;
    const ush* bh = Wth + (size_t)z * 262144;
    const ush* bl = Wtl + (size_t)z * 262144;
    if (z == 0)
        gemm3_body<1>(lds[0], lds[1], mt, nt, Xh, Xl, bh, bl, bq, Qb, 0.125f,
                      nullptr, nullptr, nullptr, nullptr);
    else if (z == 1)
        gemm3_body<2>(lds[0], lds[1], mt, nt, Xh, Xl, bh, bl, bk, nullptr, 1.0f,
                      posA, posB, Kc, Vct);
    else
        gemm3_body<3>(lds[0], lds[1], mt, nt, Xh, Xl, bh, bl, bv, nullptr, 1.0f,
                      posA, posB, Kc, Vct);
}

__global__ __launch_bounds__(256) void gemm3_out_kernel(
    const ush* __restrict__ Ch, const ush* __restrict__ Cl,
    const ush* __restrict__ Wth, const ush* __restrict__ Wtl,
    const float* __restrict__ bo, float* __restrict__ out) {
    __shared__ char lds[2][32768];
    const int wg = (blockIdx.x & 7) * 32 + (blockIdx.x >> 3);   // 256 = 8*32
    const int mt = wg >> 2, nt = wg & 3;
    gemm3_body<0>(lds[0], lds[1], mt, nt, Ch, Cl, Wth + (size_t)3 * 262144,
                  Wtl + (size_t)3 * 262144, bo, out, 1.0f,
                  nullptr, nullptr, nullptr, nullptr);
}

// ---------------------------------------------------------------------------
// bf16 MFMA flash attention, 8 waves x 16 q-rows (unchanged from R5).
// ---------------------------------------------------------------------------
__global__ __launch_bounds__(512) void attn_mfma_kernel(
    const ush* __restrict__ Qb, const ush* __restrict__ Kc,
    const ush* __restrict__ Vct, const int* __restrict__ kcnt,
    ush* __restrict__ Xh, ush* __restrict__ Xl) {
    __shared__ ush Ks[2][4096];
    __shared__ ush Vts[2][4096];
    __shared__ ush Pl[8192];                 // 8 waves x 16 rows x 128B (swizzled)

    const int tid = threadIdx.x;
    const int lane = tid & 63, w = tid >> 6;
    const int g = lane >> 4, l15 = lane & 15;

    // flat grid -> XCD-balanced (b,h,qt): x = (h + 2b) & 7
    const int i = blockIdx.x;
    const int x7 = i & 7, local = i >> 3;
    const int b = local >> 4;
    const int h = (x7 - 2 * b) & 7;
    const int qt = local & 15;
    const int bh = b * H_ + h;

    const int sel = (h < CDR_HEADS_) ? 1 : 0;
    const int NV = kcnt[b * 2 + sel];
    const int ntiles = (NV + 63) >> 6;
    const int swz = (l15 & 7) << 4;

    bf16x8 aq[2];
    {
        const ush* qp = Qb + ((size_t)bh * T_ + qt * 128 + w * 16) * D_;
#pragma unroll
        for (int kc = 0; kc < 2; ++kc)
            aq[kc] = __builtin_bit_cast(bf16x8,
                *(const int4*)(qp + l15 * D_ + kc * 32 + g * 8));
    }

    f32x4 cacc[4];
#pragma unroll
    for (int db = 0; db < 4; ++db)
#pragma unroll
        for (int r = 0; r < 4; ++r) cacc[db][r] = 0.f;
    float mr = -INFINITY, lr = 0.f;

    const char* ktiles = (const char*)(Kc + (size_t)bh * (32 * 4096));
    const char* vtiles = (const char*)(Vct + (size_t)bh * (32 * 4096));
    char* Pw = (char*)Pl + w * 2048;
    const int lwo = w * 512;

    gload16(ktiles + lwo * 2 + lane * 16, &Ks[0][lwo]);
    gload16(vtiles + lwo * 2 + lane * 16, &Vts[0][lwo]);
    __syncthreads();

    for (int t = 0; t < ntiles; ++t) {
        const int cur = t & 1, nxt = cur ^ 1;
        if (t + 1 < ntiles) {
            gload16(ktiles + (size_t)(t + 1) * 8192 + lwo * 2 + lane * 16,
                    &Ks[nxt][lwo]);
            gload16(vtiles + (size_t)(t + 1) * 8192 + lwo * 2 + lane * 16,
                    &Vts[nxt][lwo]);
        }

        // ---- swapped QK^T: s[j] = C[key][q], key = j*16+g*4+r, q = l15 ----
        bf16x8 bk[4][2];
#pragma unroll
        for (int j = 0; j < 4; ++j) {
            const int rowb = (j * 16 + l15) * 128;
            bk[j][0] = __builtin_bit_cast(bf16x8,
                *(const int4*)((const char*)Ks[cur] + ((rowb + g * 16) ^ swz)));
            bk[j][1] = __builtin_bit_cast(bf16x8,
                *(const int4*)((const char*)Ks[cur] + ((rowb + 64 + g * 16) ^ swz)));
        }
        f32x4 s[4];
        const f32x4 z4 = {0.f, 0.f, 0.f, 0.f};
        __builtin_amdgcn_s_setprio(1);
#pragma unroll
        for (int j = 0; j < 4; ++j) s[j] = MFMA16(bk[j][0], aq[0], z4);
#pragma unroll
        for (int j = 0; j < 4; ++j) s[j] = MFMA16(bk[j][1], aq[1], s[j]);
        __builtin_amdgcn_s_setprio(0);

        const int kb0 = t * 64;
        if (kb0 + 64 > NV) {
#pragma unroll
            for (int j = 0; j < 4; ++j)
#pragma unroll
                for (int r = 0; r < 4; ++r)
                    if (kb0 + j * 16 + g * 4 + r >= NV) s[j][r] = -INFINITY;
        }

        // ---- online softmax with defer-max ----
        float pmax = s[0][0];
#pragma unroll
        for (int j = 0; j < 4; ++j)
#pragma unroll
            for (int r = 0; r < 4; ++r) pmax = fmaxf(pmax, s[j][r]);
        pmax = fmaxf(pmax, __shfl_xor(pmax, 16));
        pmax = fmaxf(pmax, __shfl_xor(pmax, 32));
        if (!__all(pmax <= mr + 8.f)) {
            const float mn = fmaxf(mr, pmax);
            const float rr = __expf(mr - mn);
            mr = mn;
            lr *= rr;
#pragma unroll
            for (int r = 0; r < 4; ++r) {
                const float rrq = __shfl(rr, g * 4 + r, 16);
#pragma unroll
                for (int db = 0; db < 4; ++db) cacc[db][r] *= rrq;
            }
        }
        float sum = 0.f;
#pragma unroll
        for (int j = 0; j < 4; ++j)
#pragma unroll
            for (int r = 0; r < 4; ++r) {
                const float p = __expf(s[j][r] - mr);
                s[j][r] = p;
                sum += p;
            }
        sum += __shfl_xor(sum, 16);
        sum += __shfl_xor(sum, 32);
        lr += sum;

        // ---- P -> swizzled LDS tile: row q=l15, keys j*16+g*4..+3 ----
#pragma unroll
        for (int j = 0; j < 4; ++j) {
            const ush u0 = __builtin_bit_cast(ush, (__bf16)s[j][0]);
            const ush u1 = __builtin_bit_cast(ush, (__bf16)s[j][1]);
            const ush u2 = __builtin_bit_cast(ush, (__bf16)s[j][2]);
            const ush u3 = __builtin_bit_cast(ush, (__bf16)s[j][3]);
            uint2 pk;
            pk.x = (unsigned)u0 | ((unsigned)u1 << 16);
            pk.y = (unsigned)u2 | ((unsigned)u3 << 16);
            const int sb = (j * 2 + (g >> 1)) ^ (l15 & 7);
            *(uint2*)(Pw + l15 * 128 + sb * 16 + (g & 1) * 8) = pk;
        }

        bf16x8 pa[2];
#pragma unroll
        for (int kc = 0; kc < 2; ++kc)
            pa[kc] = __builtin_bit_cast(bf16x8,
                *(const int4*)(Pw + l15 * 128 + (((kc * 4 + g) ^ (l15 & 7)) << 4)));
        __builtin_amdgcn_s_setprio(1);
#pragma unroll
        for (int kc = 0; kc < 2; ++kc)
#pragma unroll
            for (int db = 0; db < 4; ++db) {
                bf16x8 vbf = __builtin_bit_cast(bf16x8,
                    *(const int4*)((const char*)Vts[cur] +
                        ((((db * 16 + l15) * 128) + kc * 64 + g * 16) ^ swz)));
                cacc[db] = MFMA16(pa[kc], vbf, cacc[db]);
            }
        __builtin_amdgcn_s_setprio(0);

        __syncthreads();
    }

    // ---- fused epilogue: normalize + hi/lo decompose -> swizzled Xh/Xl ----
    const int mt = b * 16 + qt;
#pragma unroll
    for (int r = 0; r < 4; ++r) {
        const float lrq = __shfl(lr, g * 4 + r, 16);
        const float inv = 1.f / lrq;
        const int ml = w * 16 + g * 4 + r;
#pragma unroll
        for (int db = 0; db < 4; ++db) {
            const int col = h * 64 + db * 16 + l15;
            const float val = cacc[db][r] * inv;
            const __bf16 hb = (__bf16)val;
            const __bf16 lb2 = (__bf16)(val - (float)hb);
            const int kt2 = col >> 5;
            const int cidx = (col >> 3) & 3;
            const size_t tb = ((size_t)mt * 16 + kt2) * 4096;
            const int boff = ml * 64 + ((cidx ^ ((ml >> 1) & 3)) << 4) + (l15 & 7) * 2;
            *(ush*)((char*)(Xh + tb) + boff) = __builtin_bit_cast(ush, hb);
            *(ush*)((char*)(Xl + tb) + boff) = __builtin_bit_cast(ush, lb2);
        }
    }
}

// ---------------------------------------------------------------------------
extern "C" void kernel_launch(void* const* d_in, const int* in_sizes, int n_in,
                              void* d_out, int out_size, void* d_ws, size_t ws_size,
                              hipStream_t stream) {
    const float* x    = (const float*)d_in[0];
    const int*   mask = (const int*)d_in[1];
    const int*   cdrs = (const int*)d_in[2];
    const float* Wq   = (const float*)d_in[3];
    const float* bq   = (const float*)d_in[4];
    const float* Wk   = (const float*)d_in[5];
    const float* bk   = (const float*)d_in[6];
    const float* Wv   = (const float*)d_in[7];
    const float* bv   = (const float*)d_in[8];
    const float* Wo   = (const float*)d_in[9];
    const float* bo   = (const float*)d_in[10];
    float* out = (float*)d_out;

    const size_t per = (size_t)B_ * H_ * T_ * D_;    // 4M elements
    ush* Qb  = (ush*)d_ws;                           // bf16 [B,H,T,D]
    ush* Kc  = Qb + per;                             // swizzled K tiles
    ush* Vct = Kc + per;                             // swizzled V^T tiles
    ush* Xh  = Vct + per;                            // x / ctx hi tiles
    ush* Xl  = Xh + per;                             // x / ctx lo tiles
    ush* Wth = Xl + per;                             // 4 matrices W^T hi
    ush* Wtl = Wth + 4 * 262144;                     // 4 matrices W^T lo
    int* posA = (int*)(Wtl + 4 * 262144);
    int* posB = posA + NROWS;
    int* kcnt = posB + NROWS;

    prep_kernel<<<2564, 256, 0, stream>>>(x, Wq, Wk, Wv, Wo, mask, cdrs,
                                          Xh, Xl, Wth, Wtl, posA, posB, kcnt);

    gemm3_qkv_kernel<<<768, 256, 0, stream>>>(
        Xh, Xl, Wth, Wtl, bq, bk, bv, Qb, posA, posB, Kc, Vct);

    attn_mfma_kernel<<<512, 512, 0, stream>>>(Qb, Kc, Vct, kcnt, Xh, Xl);

    gemm3_out_kernel<<<256, 256, 0, stream>>>(Xh, Xl, Wth, Wtl, bo, out);
}